// Round 4
// baseline (497.042 us; speedup 1.0000x reference)
//
#include <hip/hip_runtime.h>
#include <stdint.h>
#include <math.h>

#define B_    2
#define T_    2048
#define DIM_  2048
#define H_    16
#define DC_   512
#define DCQ_  1536
#define NROWS (B_*T_)   // 4096
#define NITEMS 512

typedef unsigned short u16;
typedef __attribute__((ext_vector_type(8))) __bf16 bf16x8;
typedef __attribute__((ext_vector_type(4))) float  f32x4;
typedef __attribute__((ext_vector_type(8))) unsigned short u16x8;
typedef __attribute__((ext_vector_type(4))) float  f4v;

__device__ __forceinline__ u16 f2bf(float f){
  unsigned u = __float_as_uint(f);
  u += 0x7FFFu + ((u >> 16) & 1u);   // RNE
  return (u16)(u >> 16);
}
__device__ __forceinline__ float bf2f(u16 h){ return __uint_as_float(((unsigned)h) << 16); }

// async global->LDS, 16B per lane; LDS dest = wave-uniform base + lane*16.
__device__ __forceinline__ void gld_lds16(const void* g, void* l){
  auto gp = reinterpret_cast<__attribute__((address_space(1))) unsigned int*>(
      reinterpret_cast<uintptr_t>(g));
  auto lp = reinterpret_cast<__attribute__((address_space(3))) unsigned int*>(
      reinterpret_cast<uintptr_t>(l));
  __builtin_amdgcn_global_load_lds(gp, lp, 16, 0, 0);
}

__device__ __forceinline__ f32x4 mfma16(bf16x8 a, bf16x8 b, f32x4 c){
  return __builtin_amdgcn_mfma_f32_16x16x32_bf16(a, b, c, 0, 0, 0);
}

// ---------------- dtype detect + ticket reset
__global__ void k_detect(const u16* cosr, int* flag, int* ticket){
  if (threadIdx.x == 0){
    *flag = (cosr[0] == (u16)0x3F80u) ? 1 : 0;
    *ticket = 0;
  }
}

// ---------------- convert to bf16
__global__ void k_conv(const void* __restrict__ src, u16* __restrict__ dst, int n4, const int* flag){
  int id = blockIdx.x * 256 + threadIdx.x;
  if (id >= n4) return;
  if (*flag){
    reinterpret_cast<uint2*>(dst)[id] = reinterpret_cast<const uint2*>(src)[id];
  } else {
    f4v v = reinterpret_cast<const f4v*>(src)[id];
    unsigned lo = (unsigned)f2bf(v.x) | ((unsigned)f2bf(v.y) << 16);
    unsigned hi = (unsigned)f2bf(v.z) | ((unsigned)f2bf(v.w) << 16);
    reinterpret_cast<uint2*>(dst)[id] = make_uint2(lo, hi);
  }
}

// ---------------- transpose+convert to bf16 with optional column packing.
__global__ void k_transpose(const void* __restrict__ src, u16* __restrict__ dst,
                            int srcStride, int dstStride, int cblk, const int* flag){
  __shared__ u16 tile[64][72];
  const int r0 = blockIdx.y << 6, c0 = blockIdx.x * cblk;
  const int tid = threadIdx.x;
  const int f = *flag;
  #pragma unroll
  for (int i = 0; i < 2; ++i){
    int task = (i << 8) + tid;
    int r = task >> 3, c8 = (task & 7) << 3;
    if (f){
      const u16* p = (const u16*)src + (size_t)(r0 + r) * srcStride + c0 + c8;
      u16x8 v = *reinterpret_cast<const u16x8*>(p);
      #pragma unroll
      for (int j = 0; j < 8; ++j) tile[r][c8 + j] = v[j];
    } else {
      const float* p = (const float*)src + (size_t)(r0 + r) * srcStride + c0 + c8;
      f4v a = reinterpret_cast<const f4v*>(p)[0];
      f4v b = reinterpret_cast<const f4v*>(p)[1];
      tile[r][c8+0]=f2bf(a.x); tile[r][c8+1]=f2bf(a.y); tile[r][c8+2]=f2bf(a.z); tile[r][c8+3]=f2bf(a.w);
      tile[r][c8+4]=f2bf(b.x); tile[r][c8+5]=f2bf(b.y); tile[r][c8+6]=f2bf(b.z); tile[r][c8+7]=f2bf(b.w);
    }
  }
  __syncthreads();
  #pragma unroll
  for (int i = 0; i < 2; ++i){
    int task = (i << 8) + tid;
    int rr = task >> 3, cc8 = (task & 7) << 3;
    u16x8 v;
    #pragma unroll
    for (int j = 0; j < 8; ++j) v[j] = tile[cc8 + j][rr];
    *reinterpret_cast<u16x8*>(dst + (size_t)((blockIdx.x << 6) + rr) * dstStride + r0 + cc8) = v;
  }
}

// ---------------- build vT[bh][d][t] from kvP cols 1024 + h*128 + d
__global__ void k_vt(const u16* __restrict__ kvP, u16* __restrict__ vT){
  __shared__ u16 tile[64][72];
  const int t0 = blockIdx.x << 6, d0 = blockIdx.y << 6, bh = blockIdx.z;
  const int b = bh >> 4, h = bh & 15;
  const int tid = threadIdx.x;
  #pragma unroll
  for (int i = 0; i < 2; ++i){
    int task = (i << 8) + tid;
    int r = task >> 3, c8 = (task & 7) << 3;
    const u16* p = kvP + (size_t)(b * T_ + t0 + r) * 3072 + 1024 + h * 128 + d0 + c8;
    u16x8 v = *reinterpret_cast<const u16x8*>(p);
    #pragma unroll
    for (int j = 0; j < 8; ++j) tile[r][c8 + j] = v[j];
  }
  __syncthreads();
  #pragma unroll
  for (int i = 0; i < 2; ++i){
    int task = (i << 8) + tid;
    int rr = task >> 3, cc8 = (task & 7) << 3;
    u16x8 v;
    #pragma unroll
    for (int j = 0; j < 8; ++j) v[j] = tile[cc8 + j][rr];
    *reinterpret_cast<u16x8*>(vT + ((size_t)bh * 128 + d0 + rr) * T_ + t0 + cc8) = v;
  }
}

// ---------------- GEMM: C(MxN) = A(MxK, lda) * Bt(NxK row-major)  [bf16 in, fp32 acc]
__global__ __launch_bounds__(256) void k_gemm(const u16* __restrict__ A, int lda,
                                              const u16* __restrict__ Bt,
                                              u16* __restrict__ C, int ldc,
                                              int M, int N, int K, float oscale,
                                              void* outp, const int* flag){
  __shared__ alignas(16) u16 As[128 * 64];
  __shared__ alignas(16) u16 Bs[128 * 64];
  const int tid = threadIdx.x;
  const int wid = tid >> 6, lane = tid & 63;
  const int m0 = blockIdx.x << 7, n0 = blockIdx.y << 7;
  const int wr = wid >> 1, wc = wid & 1;
  const int l16 = lane & 15, lk = (lane >> 4) << 3;
  const int srow = tid >> 3, scol = (tid & 7) << 3;
  f32x4 acc[4][4] = {};
  const int nkt = K >> 6;
  for (int kt = 0; kt < nkt; ++kt){
    const int kb = kt << 6;
    #pragma unroll
    for (int i = 0; i < 4; ++i){
      int r = (i << 5) + srow;
      gld_lds16(A  + (size_t)(m0 + r) * lda + kb + scol, &As[(i << 11) + (wid << 9)]);
      gld_lds16(Bt + (size_t)(n0 + r) * K   + kb + scol, &Bs[(i << 11) + (wid << 9)]);
    }
    __syncthreads();
    #pragma unroll
    for (int ks = 0; ks < 2; ++ks){
      bf16x8 af[4], bfr[4];
      #pragma unroll
      for (int mi = 0; mi < 4; ++mi)
        af[mi] = *reinterpret_cast<const bf16x8*>(&As[((wr << 6) + (mi << 4) + l16) * 64 + (ks << 5) + lk]);
      #pragma unroll
      for (int ni = 0; ni < 4; ++ni)
        bfr[ni] = *reinterpret_cast<const bf16x8*>(&Bs[((wc << 6) + (ni << 4) + l16) * 64 + (ks << 5) + lk]);
      #pragma unroll
      for (int mi = 0; mi < 4; ++mi)
        #pragma unroll
        for (int ni = 0; ni < 4; ++ni)
          acc[mi][ni] = mfma16(af[mi], bfr[ni], acc[mi][ni]);
    }
    __syncthreads();
  }
  const int r4 = (lane >> 4) << 2;
  const int f = flag ? *flag : 1;
  #pragma unroll
  for (int mi = 0; mi < 4; ++mi){
    int row = m0 + (wr << 6) + (mi << 4) + r4;
    #pragma unroll
    for (int ni = 0; ni < 4; ++ni){
      int col = n0 + (wc << 6) + (ni << 4) + l16;
      #pragma unroll
      for (int j = 0; j < 4; ++j){
        float v = acc[mi][ni][j] * oscale;
        if (outp){
          if (f) ((u16*)outp)[(size_t)(row + j) * ldc + col] = f2bf(v);
          else   ((float*)outp)[(size_t)(row + j) * ldc + col] = v;
        } else {
          C[(size_t)(row + j) * ldc + col] = f2bf(v);
        }
      }
    }
  }
}

// ---------------- RoPE from xc cols 2048..2175 (stride 2176); q-part pre-scaled by 1/sqrt(D)*log2e
__global__ void k_rope(const u16* __restrict__ ropes, const void* __restrict__ cosp,
                       const void* __restrict__ sinp, const int* flag,
                       u16* __restrict__ krope, u16* __restrict__ qrope){
  int id = blockIdx.x * 256 + threadIdx.x;
  if (id >= NROWS * 128) return;
  int row = id >> 7, c = id & 127;
  int t = row & (T_ - 1);
  int d = c & 63, i = d & 31;
  float cs, sn;
  if (*flag){ cs = bf2f(((const u16*)cosp)[t * 32 + i]); sn = bf2f(((const u16*)sinp)[t * 32 + i]); }
  else      { cs = ((const float*)cosp)[t * 32 + i];     sn = ((const float*)sinp)[t * 32 + i]; }
  int base = c & 64;
  float t1 = bf2f(ropes[(size_t)row * 2176 + base + i]);
  float t2 = bf2f(ropes[(size_t)row * 2176 + base + 32 + i]);
  float v = (d < 32) ? (t1 * cs - t2 * sn) : (t2 * cs + t1 * sn);
  if (c >= 64) v *= 0.12753139626374414f;   // 1/sqrt(128) * log2(e), folded into q
  ((c < 64) ? krope : qrope)[(size_t)row * 64 + d] = f2bf(v);
}

// ---------------- causal flash attention, persistent blocks + ticket, T14 reg-staged prefetch.
// Item = (qt, bh): 128 q-rows, 4 waves x 32 rows. KV tiles of 64, single LDS buffer.
// LDS (48KB): Ks [64][128] @0, Vs [128][64] @8192, Ps [32][64] per wave @16384 + wid*2048.
// All XOR-swizzled (chunk ^= row&7 within 64-col halves). Q pre-scaled -> no per-tile scale.
__global__ __launch_bounds__(256, 2) void k_attn(const u16* __restrict__ qP,
                                                 const u16* __restrict__ kvP,
                                                 const u16* __restrict__ vT,
                                                 const u16* __restrict__ krope,
                                                 const u16* __restrict__ qrope,
                                                 u16* __restrict__ aout,
                                                 int* __restrict__ ticket){
  __shared__ alignas(16) u16 smem[24576];   // 48 KB
  __shared__ int s_item;
  const int tid = threadIdx.x, wid = tid >> 6, lane = tid & 63;
  const int l16 = lane & 15, g = lane >> 4;
  const int lk = g << 3, r4 = g << 2;
  u16* Ps = &smem[16384 + (wid << 11)];

  // tile-invariant swizzled LDS write addresses (u16 index), 8 chunks/thread
  int ldsw[8];
  #pragma unroll
  for (int r = 0; r < 8; ++r){
    int c = (r << 8) + tid;
    if (r < 4){
      int row = c >> 4, cc = c & 15;
      ldsw[r] = row * 128 + (((cc & 8) | ((cc & 7) ^ (row & 7))) << 3);
    } else {
      int cv = c - 1024, row = cv >> 3, cc = cv & 7;
      ldsw[r] = 8192 + row * 64 + ((cc ^ (row & 7)) << 3);
    }
  }

  while (true){
    if (tid == 0) s_item = atomicAdd(ticket, 1);
    __syncthreads();
    const int it = s_item;
    if (it >= NITEMS) break;
    const int qt = 15 - (it >> 5);          // heavy-first
    const int bh = it & 31, b = bh >> 4, h = bh & 15;
    const int q0 = qt << 7;
    const size_t bT = (size_t)b * T_;
    const u16* kvPb = kvP + bT * 3072 + (h << 6);
    const u16* krb  = krope + bT * 64;
    const u16* vTb  = vT + (size_t)bh * 128 * T_;
    const int qlo = q0 + (wid << 5);
    const int qhi = qlo + 31;
    const int nkv = (q0 >> 6) + 2;

    auto LOADT = [&](uint4* stg, int k0){
      #pragma unroll
      for (int r = 0; r < 8; ++r){
        int c = (r << 8) + tid;
        const u16* src;
        if (r < 4){
          int row = c >> 4, col0 = (c & 15) << 3;
          src = (col0 < 64) ? (kvPb + (size_t)(k0 + row) * 3072 + col0)
                            : (krb  + (size_t)(k0 + row) * 64 + (col0 - 64));
        } else {
          int cv = c - 1024, row = cv >> 3;
          src = vTb + (size_t)row * T_ + k0 + ((cv & 7) << 3);
        }
        stg[r] = *reinterpret_cast<const uint4*>(src);
      }
    };

    // Q fragments (pre-scaled by 1/sqrt(D)*log2e upstream)
    bf16x8 qf[2][4];
    #pragma unroll
    for (int rg = 0; rg < 2; ++rg){
      size_t grow = bT + q0 + (wid << 5) + (rg << 4) + l16;
      #pragma unroll
      for (int ks = 0; ks < 4; ++ks){
        int d = (ks << 5) + lk;
        const u16* src = (ks < 2) ? (qP + grow * 1024 + (h << 6) + d)
                                  : (qrope + grow * 64 + (d - 64));
        qf[rg][ks] = *reinterpret_cast<const bf16x8*>(src);
      }
    }
    f32x4 o[2][8] = {};
    float m[2][4], l[2][4];
    #pragma unroll
    for (int rg = 0; rg < 2; ++rg)
      #pragma unroll
      for (int j = 0; j < 4; ++j){ m[rg][j] = -3e38f; l[rg][j] = 0.f; }

    uint4 stg[8];
    LOADT(stg, 0);

    for (int kv = 0; kv < nkv; ++kv){
      const int k0 = kv << 6;
      __syncthreads();                      // prev tile's LDS reads complete
      #pragma unroll
      for (int r = 0; r < 8; ++r)
        *reinterpret_cast<uint4*>(&smem[ldsw[r]]) = stg[r];
      __syncthreads();                      // tile visible
      if (kv + 1 < nkv) LOADT(stg, (kv + 1) << 6);   // prefetch next (overlaps compute)
      if (k0 <= qhi){
        // ---- S = Q K^T
        f32x4 s[2][4] = {};
        #pragma unroll
        for (int ks = 0; ks < 4; ++ks){
          int colsw = ((ks << 5) + lk) ^ ((l16 & 7) << 3);
          #pragma unroll
          for (int n = 0; n < 4; ++n){
            bf16x8 kf = *reinterpret_cast<const bf16x8*>(&smem[((n << 4) + l16) * 128 + colsw]);
            s[0][n] = mfma16(qf[0][ks], kf, s[0][n]);
            s[1][n] = mfma16(qf[1][ks], kf, s[1][n]);
          }
        }
        // ---- mask only on non-full tiles (wave-uniform branch)
        if (k0 + 63 > qlo){
          #pragma unroll
          for (int rg = 0; rg < 2; ++rg)
            #pragma unroll
            for (int j = 0; j < 4; ++j){
              const int tq = q0 + (wid << 5) + (rg << 4) + r4 + j;
              #pragma unroll
              for (int n = 0; n < 4; ++n){
                int tk = k0 + (n << 4) + l16;
                s[rg][n][j] = (tk <= tq) ? s[rg][n][j] : -3e38f;
              }
            }
        }
        // ---- row max + defer check
        float mx8[2][4];
        bool grow_ = false;
        #pragma unroll
        for (int rg = 0; rg < 2; ++rg){
          #pragma unroll
          for (int j = 0; j < 4; ++j){
            float mx = fmaxf(fmaxf(s[rg][0][j], s[rg][1][j]), fmaxf(s[rg][2][j], s[rg][3][j]));
            mx = fmaxf(mx, __shfl_xor(mx, 1));
            mx = fmaxf(mx, __shfl_xor(mx, 2));
            mx = fmaxf(mx, __shfl_xor(mx, 4));
            mx = fmaxf(mx, __shfl_xor(mx, 8));
            mx8[rg][j] = mx;
            grow_ |= (mx > m[rg][j] + 8.f);
          }
        }
        if (__ballot(grow_)){
          #pragma unroll
          for (int rg = 0; rg < 2; ++rg)
            #pragma unroll
            for (int j = 0; j < 4; ++j){
              float mnew = fmaxf(m[rg][j], mx8[rg][j]);
              float alpha = exp2f(m[rg][j] - mnew);
              m[rg][j] = mnew;
              l[rg][j] *= alpha;
              #pragma unroll
              for (int db = 0; db < 8; ++db) o[rg][db][j] *= alpha;
            }
        }
        // ---- P = exp2(s - m), row sums, store P
        #pragma unroll
        for (int rg = 0; rg < 2; ++rg){
          #pragma unroll
          for (int j = 0; j < 4; ++j){
            float rs = 0.f;
            const int prow = ((rg << 4) + r4 + j) << 6;
            const int psw = ((r4 + j) & 7) << 3;
            #pragma unroll
            for (int n = 0; n < 4; ++n){
              float p = exp2f(s[rg][n][j] - m[rg][j]);
              rs += p;
              Ps[prow + (((n << 4) + l16) ^ psw)] = f2bf(p);
            }
            rs += __shfl_xor(rs, 1); rs += __shfl_xor(rs, 2);
            rs += __shfl_xor(rs, 4); rs += __shfl_xor(rs, 8);
            l[rg][j] += rs;
          }
        }
        // ---- O += P V
        #pragma unroll
        for (int ks2 = 0; ks2 < 2; ++ks2){
          int colsw = ((ks2 << 5) + lk) ^ ((l16 & 7) << 3);
          bf16x8 pa0 = *reinterpret_cast<const bf16x8*>(&Ps[l16 * 64 + colsw]);
          bf16x8 pa1 = *reinterpret_cast<const bf16x8*>(&Ps[(16 + l16) * 64 + colsw]);
          #pragma unroll
          for (int db = 0; db < 8; ++db){
            bf16x8 vb = *reinterpret_cast<const bf16x8*>(&smem[8192 + ((db << 4) + l16) * 64 + colsw]);
            o[0][db] = mfma16(pa0, vb, o[0][db]);
            o[1][db] = mfma16(pa1, vb, o[1][db]);
          }
        }
      }
    }
    // ---- epilogue
    #pragma unroll
    for (int rg = 0; rg < 2; ++rg){
      #pragma unroll
      for (int j = 0; j < 4; ++j){
        float rinv = 1.f / l[rg][j];
        const int tq = q0 + (wid << 5) + (rg << 4) + r4 + j;
        u16* dst = aout + (bT + tq) * 2048 + (h << 7) + l16;
        #pragma unroll
        for (int db = 0; db < 8; ++db)
          dst[db << 4] = f2bf(o[rg][db][j] * rinv);
      }
    }
    __syncthreads();                        // all epilogue LDS-independent; re-sync before next item
  }
}

extern "C" void kernel_launch(void* const* d_in, const int* in_sizes, int n_in,
                              void* d_out, int out_size, void* d_ws, size_t ws_size,
                              hipStream_t stream){
  const void* x       = d_in[0];
  const void* cosp    = d_in[1];
  const void* sinp    = d_in[2];
  const void* w_kv    = d_in[3];
  const void* w_kdec  = d_in[4];
  const void* w_vdec  = d_in[5];
  const void* w_qc    = d_in[6];
  const void* w_qdec  = d_in[7];
  const void* w_krope = d_in[8];
  const void* w_qrope = d_in[9];
  const void* w_o     = d_in[10];

  char* ws = (char*)d_ws;
  size_t off = 0;
  auto alloc = [&](size_t bytes){ void* p = ws + off; off += (bytes + 255) & ~(size_t)255; return p; };
  int* flag     = (int*)alloc(256);
  int* ticket   = (int*)alloc(256);
  u16* x_bf     = (u16*)alloc((size_t)NROWS * DIM_ * 2);
  u16* w_c1T    = (u16*)alloc((size_t)2176 * DIM_ * 2);      // [kvT(512); qcT(1536); kropeT(64); qropeT(64)] x 2048
  u16* w_kvdT   = (u16*)alloc((size_t)3072 * DC_ * 2);       // [kdecPackedT(1024); vdecT(2048)] x 512
  u16* w_qdPT   = (u16*)alloc((size_t)1024 * DCQ_ * 2);      // packed qdecT (1024 x 1536)
  u16* w_oT     = (u16*)alloc((size_t)DIM_ * DIM_ * 2);
  u16* xc       = (u16*)alloc((size_t)NROWS * 2176 * 2);     // [c_kv(512) | c_q(1536) | ropes(128)]
  u16* qP       = (u16*)alloc((size_t)NROWS * 1024 * 2);     // packed q decode (pre-scaled)
  u16* kvP      = (u16*)alloc((size_t)NROWS * 3072 * 2);     // [kPacked(1024) | v(2048)]
  u16* krope    = (u16*)alloc((size_t)NROWS * 64 * 2);
  u16* qrope    = (u16*)alloc((size_t)NROWS * 64 * 2);       // pre-scaled
  u16* vT       = (u16*)alloc((size_t)32 * 128 * T_ * 2);    // [bh][d][t]
  u16* aout     = (u16*)alloc((size_t)NROWS * DIM_ * 2);
  (void)in_sizes; (void)n_in; (void)out_size; (void)ws_size;

  const float SC2 = 0.12753139626374414f;   // 1/sqrt(128) * log2(e)

  hipLaunchKernelGGL(k_detect, dim3(1), dim3(64), 0, stream, (const u16*)cosp, flag, ticket);

  int n4 = NROWS * DIM_ / 4;
  hipLaunchKernelGGL(k_conv, dim3((n4 + 255) / 256), dim3(256), 0, stream, x, x_bf, n4, flag);

  // weight transposes into combined buffers (grid = (dstRows/64, srcRows/64))
  hipLaunchKernelGGL(k_transpose, dim3(8,  32), dim3(256), 0, stream, w_kv,    w_c1T,                        512,  2048, 64,  flag);
  hipLaunchKernelGGL(k_transpose, dim3(24, 32), dim3(256), 0, stream, w_qc,    w_c1T + (size_t)512 * 2048,   1536, 2048, 64,  flag);
  hipLaunchKernelGGL(k_transpose, dim3(1,  32), dim3(256), 0, stream, w_krope, w_c1T + (size_t)2048 * 2048,  64,   2048, 64,  flag);
  hipLaunchKernelGGL(k_transpose, dim3(1,  32), dim3(256), 0, stream, w_qrope, w_c1T + (size_t)2112 * 2048,  64,   2048, 64,  flag);
  hipLaunchKernelGGL(k_transpose, dim3(16, 8),  dim3(256), 0, stream, w_kdec,  w_kvdT,                       2048, 512,  128, flag);
  hipLaunchKernelGGL(k_transpose, dim3(32, 8),  dim3(256), 0, stream, w_vdec,  w_kvdT + (size_t)1024 * 512,  2048, 512,  64,  flag);
  hipLaunchKernelGGL(k_transpose, dim3(16, 24), dim3(256), 0, stream, w_qdec,  w_qdPT,                       2048, 1536, 128, flag);
  hipLaunchKernelGGL(k_transpose, dim3(32, 32), dim3(256), 0, stream, w_o,     w_oT,                         2048, 2048, 64,  flag);

  // G13: xc = x @ [w_kv | w_qc | w_krope | w_qrope]  (4096 x 2176, K=2048)
  hipLaunchKernelGGL(k_gemm, dim3(NROWS/128, 2176/128), dim3(256), 0, stream,
                     x_bf, DIM_, w_c1T, xc, 2176, NROWS, 2176, DIM_, 1.0f, (void*)nullptr, (const int*)nullptr);
  // G2: kvP = xc[:, :512] @ [w_kdecP | w_vdec]   (4096 x 3072, K=512)
  hipLaunchKernelGGL(k_gemm, dim3(NROWS/128, 3072/128), dim3(256), 0, stream,
                     xc, 2176, w_kvdT, kvP, 3072, NROWS, 3072, DC_, 1.0f, (void*)nullptr, (const int*)nullptr);
  // G4: qP = xc[:, 512:2048] @ w_qdecP   (4096 x 1024, K=1536), pre-scaled for softmax
  hipLaunchKernelGGL(k_gemm, dim3(NROWS/128, 1024/128), dim3(256), 0, stream,
                     xc + 512, 2176, w_qdPT, qP, 1024, NROWS, 1024, DCQ_, SC2, (void*)nullptr, (const int*)nullptr);
  // RoPE (q-part pre-scaled)
  hipLaunchKernelGGL(k_rope, dim3(NROWS * 128 / 256), dim3(256), 0, stream,
                     xc + 2048, cosp, sinp, flag, krope, qrope);
  // vT[bh][d][t]
  hipLaunchKernelGGL(k_vt, dim3(T_/64, 2, 32), dim3(256), 0, stream, kvP, vT);
  // attention (persistent, 512 worker blocks = 2/CU)
  hipLaunchKernelGGL(k_attn, dim3(512), dim3(256), 0, stream,
                     qP, kvP, vT, krope, qrope, aout, ticket);
  // G5: out = aout @ w_o  (writes d_out; dtype per flag)
  hipLaunchKernelGGL(k_gemm, dim3(NROWS/128, DIM_/128), dim3(256), 0, stream,
                     aout, DIM_, w_oT, (u16*)nullptr, DIM_, NROWS, DIM_, DIM_, 1.0f, d_out, (const int*)flag);
}

// Round 5
// 419.873 us; speedup vs baseline: 1.1838x; 1.1838x over previous
//
#include <hip/hip_runtime.h>
#include <stdint.h>
#include <math.h>

#define B_    2
#define T_    2048
#define DIM_  2048
#define H_    16
#define DC_   512
#define DCQ_  1536
#define NROWS (B_*T_)   // 4096
#define NITEMS 512

typedef unsigned short u16;
typedef __attribute__((ext_vector_type(8))) __bf16 bf16x8;
typedef __attribute__((ext_vector_type(4))) float  f32x4;
typedef __attribute__((ext_vector_type(8))) unsigned short u16x8;
typedef __attribute__((ext_vector_type(4))) float  f4v;

__device__ __forceinline__ u16 f2bf(float f){
  unsigned u = __float_as_uint(f);
  u += 0x7FFFu + ((u >> 16) & 1u);   // RNE
  return (u16)(u >> 16);
}
__device__ __forceinline__ float bf2f(u16 h){ return __uint_as_float(((unsigned)h) << 16); }

// async global->LDS, 16B per lane; LDS dest = wave-uniform base + lane*16.
__device__ __forceinline__ void gld_lds16(const void* g, void* l){
  auto gp = reinterpret_cast<__attribute__((address_space(1))) unsigned int*>(
      reinterpret_cast<uintptr_t>(g));
  auto lp = reinterpret_cast<__attribute__((address_space(3))) unsigned int*>(
      reinterpret_cast<uintptr_t>(l));
  __builtin_amdgcn_global_load_lds(gp, lp, 16, 0, 0);
}

__device__ __forceinline__ f32x4 mfma16(bf16x8 a, bf16x8 b, f32x4 c){
  return __builtin_amdgcn_mfma_f32_16x16x32_bf16(a, b, c, 0, 0, 0);
}

// ---------------- dtype detect + ticket reset
__global__ void k_detect(const u16* cosr, int* flag, int* ticket){
  if (threadIdx.x == 0){
    *flag = (cosr[0] == (u16)0x3F80u) ? 1 : 0;
    *ticket = 0;
  }
}

// ---------------- convert to bf16
__global__ void k_conv(const void* __restrict__ src, u16* __restrict__ dst, int n4, const int* flag){
  int id = blockIdx.x * 256 + threadIdx.x;
  if (id >= n4) return;
  if (*flag){
    reinterpret_cast<uint2*>(dst)[id] = reinterpret_cast<const uint2*>(src)[id];
  } else {
    f4v v = reinterpret_cast<const f4v*>(src)[id];
    unsigned lo = (unsigned)f2bf(v.x) | ((unsigned)f2bf(v.y) << 16);
    unsigned hi = (unsigned)f2bf(v.z) | ((unsigned)f2bf(v.w) << 16);
    reinterpret_cast<uint2*>(dst)[id] = make_uint2(lo, hi);
  }
}

// ---------------- transpose+convert to bf16 with optional column packing.
__global__ void k_transpose(const void* __restrict__ src, u16* __restrict__ dst,
                            int srcStride, int dstStride, int cblk, const int* flag){
  __shared__ u16 tile[64][72];
  const int r0 = blockIdx.y << 6, c0 = blockIdx.x * cblk;
  const int tid = threadIdx.x;
  const int f = *flag;
  #pragma unroll
  for (int i = 0; i < 2; ++i){
    int task = (i << 8) + tid;
    int r = task >> 3, c8 = (task & 7) << 3;
    if (f){
      const u16* p = (const u16*)src + (size_t)(r0 + r) * srcStride + c0 + c8;
      u16x8 v = *reinterpret_cast<const u16x8*>(p);
      #pragma unroll
      for (int j = 0; j < 8; ++j) tile[r][c8 + j] = v[j];
    } else {
      const float* p = (const float*)src + (size_t)(r0 + r) * srcStride + c0 + c8;
      f4v a = reinterpret_cast<const f4v*>(p)[0];
      f4v b = reinterpret_cast<const f4v*>(p)[1];
      tile[r][c8+0]=f2bf(a.x); tile[r][c8+1]=f2bf(a.y); tile[r][c8+2]=f2bf(a.z); tile[r][c8+3]=f2bf(a.w);
      tile[r][c8+4]=f2bf(b.x); tile[r][c8+5]=f2bf(b.y); tile[r][c8+6]=f2bf(b.z); tile[r][c8+7]=f2bf(b.w);
    }
  }
  __syncthreads();
  #pragma unroll
  for (int i = 0; i < 2; ++i){
    int task = (i << 8) + tid;
    int rr = task >> 3, cc8 = (task & 7) << 3;
    u16x8 v;
    #pragma unroll
    for (int j = 0; j < 8; ++j) v[j] = tile[cc8 + j][rr];
    *reinterpret_cast<u16x8*>(dst + (size_t)((blockIdx.x << 6) + rr) * dstStride + r0 + cc8) = v;
  }
}

// ---------------- build vT[bh][d][t] from kvP cols 1024 + h*128 + d
__global__ void k_vt(const u16* __restrict__ kvP, u16* __restrict__ vT){
  __shared__ u16 tile[64][72];
  const int t0 = blockIdx.x << 6, d0 = blockIdx.y << 6, bh = blockIdx.z;
  const int b = bh >> 4, h = bh & 15;
  const int tid = threadIdx.x;
  #pragma unroll
  for (int i = 0; i < 2; ++i){
    int task = (i << 8) + tid;
    int r = task >> 3, c8 = (task & 7) << 3;
    const u16* p = kvP + (size_t)(b * T_ + t0 + r) * 3072 + 1024 + h * 128 + d0 + c8;
    u16x8 v = *reinterpret_cast<const u16x8*>(p);
    #pragma unroll
    for (int j = 0; j < 8; ++j) tile[r][c8 + j] = v[j];
  }
  __syncthreads();
  #pragma unroll
  for (int i = 0; i < 2; ++i){
    int task = (i << 8) + tid;
    int rr = task >> 3, cc8 = (task & 7) << 3;
    u16x8 v;
    #pragma unroll
    for (int j = 0; j < 8; ++j) v[j] = tile[cc8 + j][rr];
    *reinterpret_cast<u16x8*>(vT + ((size_t)bh * 128 + d0 + rr) * T_ + t0 + cc8) = v;
  }
}

// ---------------- GEMM: C(MxN) = A(MxK, lda) * Bt(NxK row-major)  [bf16 in, fp32 acc]
__global__ __launch_bounds__(256) void k_gemm(const u16* __restrict__ A, int lda,
                                              const u16* __restrict__ Bt,
                                              u16* __restrict__ C, int ldc,
                                              int M, int N, int K, float oscale,
                                              void* outp, const int* flag){
  __shared__ alignas(16) u16 As[128 * 64];
  __shared__ alignas(16) u16 Bs[128 * 64];
  const int tid = threadIdx.x;
  const int wid = tid >> 6, lane = tid & 63;
  const int m0 = blockIdx.x << 7, n0 = blockIdx.y << 7;
  const int wr = wid >> 1, wc = wid & 1;
  const int l16 = lane & 15, lk = (lane >> 4) << 3;
  const int srow = tid >> 3, scol = (tid & 7) << 3;
  f32x4 acc[4][4] = {};
  const int nkt = K >> 6;
  for (int kt = 0; kt < nkt; ++kt){
    const int kb = kt << 6;
    #pragma unroll
    for (int i = 0; i < 4; ++i){
      int r = (i << 5) + srow;
      gld_lds16(A  + (size_t)(m0 + r) * lda + kb + scol, &As[(i << 11) + (wid << 9)]);
      gld_lds16(Bt + (size_t)(n0 + r) * K   + kb + scol, &Bs[(i << 11) + (wid << 9)]);
    }
    __syncthreads();
    #pragma unroll
    for (int ks = 0; ks < 2; ++ks){
      bf16x8 af[4], bfr[4];
      #pragma unroll
      for (int mi = 0; mi < 4; ++mi)
        af[mi] = *reinterpret_cast<const bf16x8*>(&As[((wr << 6) + (mi << 4) + l16) * 64 + (ks << 5) + lk]);
      #pragma unroll
      for (int ni = 0; ni < 4; ++ni)
        bfr[ni] = *reinterpret_cast<const bf16x8*>(&Bs[((wc << 6) + (ni << 4) + l16) * 64 + (ks << 5) + lk]);
      #pragma unroll
      for (int mi = 0; mi < 4; ++mi)
        #pragma unroll
        for (int ni = 0; ni < 4; ++ni)
          acc[mi][ni] = mfma16(af[mi], bfr[ni], acc[mi][ni]);
    }
    __syncthreads();
  }
  const int r4 = (lane >> 4) << 2;
  const int f = flag ? *flag : 1;
  #pragma unroll
  for (int mi = 0; mi < 4; ++mi){
    int row = m0 + (wr << 6) + (mi << 4) + r4;
    #pragma unroll
    for (int ni = 0; ni < 4; ++ni){
      int col = n0 + (wc << 6) + (ni << 4) + l16;
      #pragma unroll
      for (int j = 0; j < 4; ++j){
        float v = acc[mi][ni][j] * oscale;
        if (outp){
          if (f) ((u16*)outp)[(size_t)(row + j) * ldc + col] = f2bf(v);
          else   ((float*)outp)[(size_t)(row + j) * ldc + col] = v;
        } else {
          C[(size_t)(row + j) * ldc + col] = f2bf(v);
        }
      }
    }
  }
}

// ---------------- RoPE from xc cols 2048..2175 (stride 2176); q-part pre-scaled by 1/sqrt(D)*log2e
__global__ void k_rope(const u16* __restrict__ ropes, const void* __restrict__ cosp,
                       const void* __restrict__ sinp, const int* flag,
                       u16* __restrict__ krope, u16* __restrict__ qrope){
  int id = blockIdx.x * 256 + threadIdx.x;
  if (id >= NROWS * 128) return;
  int row = id >> 7, c = id & 127;
  int t = row & (T_ - 1);
  int d = c & 63, i = d & 31;
  float cs, sn;
  if (*flag){ cs = bf2f(((const u16*)cosp)[t * 32 + i]); sn = bf2f(((const u16*)sinp)[t * 32 + i]); }
  else      { cs = ((const float*)cosp)[t * 32 + i];     sn = ((const float*)sinp)[t * 32 + i]; }
  int base = c & 64;
  float t1 = bf2f(ropes[(size_t)row * 2176 + base + i]);
  float t2 = bf2f(ropes[(size_t)row * 2176 + base + 32 + i]);
  float v = (d < 32) ? (t1 * cs - t2 * sn) : (t2 * cs + t1 * sn);
  if (c >= 64) v *= 0.12753139626374414f;   // 1/sqrt(128) * log2(e), folded into q
  ((c < 64) ? krope : qrope)[(size_t)row * 64 + d] = f2bf(v);
}

// ---------------- causal flash attention, persistent ticket, gload_lds double-buffer.
// Item = (qt, bh): 128 q-rows, 4 waves x 32 rows. KV tiles of 64.
// LDS EXACTLY 81920 B -> 2 blocks/CU:
//   buffer b (32KB @ b*16384 u16): Ks [64][128], Vs [128][64] @ +8192
//   Ps [32][64] per wave @ 32768 + wid*2048
// Ticket broadcast aliased into smem[0] (K-buffer 0), guarded by barriers.
// All tiles XOR-swizzled (col ^= (row&7)<<3) via pre-swizzled global sources.
__global__ __launch_bounds__(256, 2) void k_attn(const u16* __restrict__ qP,
                                                 const u16* __restrict__ kvP,
                                                 const u16* __restrict__ vT,
                                                 const u16* __restrict__ krope,
                                                 const u16* __restrict__ qrope,
                                                 u16* __restrict__ aout,
                                                 int* __restrict__ ticket){
  __shared__ alignas(16) u16 smem[40960];   // 81920 B exactly
  const int tid = threadIdx.x, wid = tid >> 6, lane = tid & 63;
  const int l16 = lane & 15, g = lane >> 4;
  const int lk = g << 3, r4 = g << 2;
  u16* Ps = &smem[32768 + (wid << 11)];

  while (true){
    if (tid == 0) *(int*)&smem[0] = atomicAdd(ticket, 1);
    __syncthreads();                        // broadcast visible
    const int it = *(const int*)&smem[0];
    __syncthreads();                        // everyone has read before staging overwrites
    if (it >= NITEMS) break;
    const int qt = 15 - (it >> 5);          // heavy-first
    const int bh = it & 31, b = bh >> 4, h = bh & 15;
    const int q0 = qt << 7;
    const size_t bT = (size_t)b * T_;
    const u16* kvPb = kvP + bT * 3072 + (h << 6);
    const u16* krb  = krope + bT * 64;
    const u16* vTb  = vT + (size_t)bh * 128 * T_;
    const int qlo = q0 + (wid << 5);
    const int qhi = qlo + 31;
    const int nkv = (q0 >> 6) + 2;

    auto STAGE = [&](int buf, int k0){
      const int base = buf << 14;           // u16 idx (32KB per buffer)
      #pragma unroll
      for (int r = 0; r < 8; ++r){
        int c = (r << 8) + tid;
        const u16* src;
        if (r < 4){
          int row = c >> 4, cc = c & 15;
          int ccx = (cc & 8) | ((cc & 7) ^ (row & 7));
          int col0 = ccx << 3;
          src = (col0 < 64) ? (kvPb + (size_t)(k0 + row) * 3072 + col0)
                            : (krb  + (size_t)(k0 + row) * 64 + (col0 - 64));
        } else {
          int cv = c - 1024;
          int row = cv >> 3, cc = cv & 7;
          int ccx = cc ^ (row & 7);
          src = vTb + (size_t)row * T_ + k0 + (ccx << 3);
        }
        gld_lds16(src, &smem[base + (((r << 8) + (wid << 6)) << 3)]);
      }
    };

    // Q fragments (pre-scaled by 1/sqrt(D)*log2e upstream)
    bf16x8 qf[2][4];
    #pragma unroll
    for (int rg = 0; rg < 2; ++rg){
      size_t grow = bT + q0 + (wid << 5) + (rg << 4) + l16;
      #pragma unroll
      for (int ks = 0; ks < 4; ++ks){
        int d = (ks << 5) + lk;
        const u16* src = (ks < 2) ? (qP + grow * 1024 + (h << 6) + d)
                                  : (qrope + grow * 64 + (d - 64));
        qf[rg][ks] = *reinterpret_cast<const bf16x8*>(src);
      }
    }
    f32x4 o[2][8] = {};
    float m[2][4], l[2][4];
    #pragma unroll
    for (int rg = 0; rg < 2; ++rg)
      #pragma unroll
      for (int j = 0; j < 4; ++j){ m[rg][j] = -3e38f; l[rg][j] = 0.f; }

    STAGE(0, 0);
    __syncthreads();                        // tile 0 resident
    int cur = 0;

    for (int kv = 0; kv < nkv; ++kv){
      const int k0 = kv << 6;
      if (kv + 1 < nkv) STAGE(cur ^ 1, (kv + 1) << 6);   // prefetch next tile
      if (k0 <= qhi){
        const int kb = cur << 14;
        // ---- S = Q K^T
        f32x4 s[2][4] = {};
        #pragma unroll
        for (int ks = 0; ks < 4; ++ks){
          int colsw = ((ks << 5) + lk) ^ ((l16 & 7) << 3);
          #pragma unroll
          for (int n = 0; n < 4; ++n){
            bf16x8 kf = *reinterpret_cast<const bf16x8*>(&smem[kb + ((n << 4) + l16) * 128 + colsw]);
            s[0][n] = mfma16(qf[0][ks], kf, s[0][n]);
            s[1][n] = mfma16(qf[1][ks], kf, s[1][n]);
          }
        }
        // ---- mask only on non-full tiles (wave-uniform branch)
        if (k0 + 63 > qlo){
          #pragma unroll
          for (int rg = 0; rg < 2; ++rg)
            #pragma unroll
            for (int j = 0; j < 4; ++j){
              const int tq = q0 + (wid << 5) + (rg << 4) + r4 + j;
              #pragma unroll
              for (int n = 0; n < 4; ++n){
                int tk = k0 + (n << 4) + l16;
                s[rg][n][j] = (tk <= tq) ? s[rg][n][j] : -3e38f;
              }
            }
        }
        // ---- row max + defer check
        float mx8[2][4];
        bool grow_ = false;
        #pragma unroll
        for (int rg = 0; rg < 2; ++rg){
          #pragma unroll
          for (int j = 0; j < 4; ++j){
            float mx = fmaxf(fmaxf(s[rg][0][j], s[rg][1][j]), fmaxf(s[rg][2][j], s[rg][3][j]));
            mx = fmaxf(mx, __shfl_xor(mx, 1));
            mx = fmaxf(mx, __shfl_xor(mx, 2));
            mx = fmaxf(mx, __shfl_xor(mx, 4));
            mx = fmaxf(mx, __shfl_xor(mx, 8));
            mx8[rg][j] = mx;
            grow_ |= (mx > m[rg][j] + 8.f);
          }
        }
        if (__ballot(grow_)){
          #pragma unroll
          for (int rg = 0; rg < 2; ++rg)
            #pragma unroll
            for (int j = 0; j < 4; ++j){
              float mnew = fmaxf(m[rg][j], mx8[rg][j]);
              float alpha = exp2f(m[rg][j] - mnew);
              m[rg][j] = mnew;
              l[rg][j] *= alpha;
              #pragma unroll
              for (int db = 0; db < 8; ++db) o[rg][db][j] *= alpha;
            }
        }
        // ---- P = exp2(s - m), row sums, store P
        #pragma unroll
        for (int rg = 0; rg < 2; ++rg){
          #pragma unroll
          for (int j = 0; j < 4; ++j){
            float rs = 0.f;
            const int prow = ((rg << 4) + r4 + j) << 6;
            const int psw = ((r4 + j) & 7) << 3;
            #pragma unroll
            for (int n = 0; n < 4; ++n){
              float p = exp2f(s[rg][n][j] - m[rg][j]);
              rs += p;
              Ps[prow + (((n << 4) + l16) ^ psw)] = f2bf(p);
            }
            rs += __shfl_xor(rs, 1); rs += __shfl_xor(rs, 2);
            rs += __shfl_xor(rs, 4); rs += __shfl_xor(rs, 8);
            l[rg][j] += rs;
          }
        }
        // ---- O += P V
        #pragma unroll
        for (int ks2 = 0; ks2 < 2; ++ks2){
          int colsw = ((ks2 << 5) + lk) ^ ((l16 & 7) << 3);
          bf16x8 pa0 = *reinterpret_cast<const bf16x8*>(&Ps[l16 * 64 + colsw]);
          bf16x8 pa1 = *reinterpret_cast<const bf16x8*>(&Ps[(16 + l16) * 64 + colsw]);
          #pragma unroll
          for (int db = 0; db < 8; ++db){
            bf16x8 vb = *reinterpret_cast<const bf16x8*>(&smem[kb + 8192 + ((db << 4) + l16) * 64 + colsw]);
            o[0][db] = mfma16(pa0, vb, o[0][db]);
            o[1][db] = mfma16(pa1, vb, o[1][db]);
          }
        }
      }
      __syncthreads();                      // drains prefetch; all reads done before buffer reuse
      cur ^= 1;
    }
    // ---- epilogue (register-only; safe before next item's ticket write)
    #pragma unroll
    for (int rg = 0; rg < 2; ++rg){
      #pragma unroll
      for (int j = 0; j < 4; ++j){
        float rinv = 1.f / l[rg][j];
        const int tq = q0 + (wid << 5) + (rg << 4) + r4 + j;
        u16* dst = aout + (bT + tq) * 2048 + (h << 7) + l16;
        #pragma unroll
        for (int db = 0; db < 8; ++db)
          dst[db << 4] = f2bf(o[rg][db][j] * rinv);
      }
    }
  }
}

extern "C" void kernel_launch(void* const* d_in, const int* in_sizes, int n_in,
                              void* d_out, int out_size, void* d_ws, size_t ws_size,
                              hipStream_t stream){
  const void* x       = d_in[0];
  const void* cosp    = d_in[1];
  const void* sinp    = d_in[2];
  const void* w_kv    = d_in[3];
  const void* w_kdec  = d_in[4];
  const void* w_vdec  = d_in[5];
  const void* w_qc    = d_in[6];
  const void* w_qdec  = d_in[7];
  const void* w_krope = d_in[8];
  const void* w_qrope = d_in[9];
  const void* w_o     = d_in[10];

  char* ws = (char*)d_ws;
  size_t off = 0;
  auto alloc = [&](size_t bytes){ void* p = ws + off; off += (bytes + 255) & ~(size_t)255; return p; };
  int* flag     = (int*)alloc(256);
  int* ticket   = (int*)alloc(256);
  u16* x_bf     = (u16*)alloc((size_t)NROWS * DIM_ * 2);
  u16* w_c1T    = (u16*)alloc((size_t)2176 * DIM_ * 2);      // [kvT(512); qcT(1536); kropeT(64); qropeT(64)] x 2048
  u16* w_kvdT   = (u16*)alloc((size_t)3072 * DC_ * 2);       // [kdecPackedT(1024); vdecT(2048)] x 512
  u16* w_qdPT   = (u16*)alloc((size_t)1024 * DCQ_ * 2);      // packed qdecT (1024 x 1536)
  u16* w_oT     = (u16*)alloc((size_t)DIM_ * DIM_ * 2);
  u16* xc       = (u16*)alloc((size_t)NROWS * 2176 * 2);     // [c_kv(512) | c_q(1536) | ropes(128)]
  u16* qP       = (u16*)alloc((size_t)NROWS * 1024 * 2);     // packed q decode (pre-scaled)
  u16* kvP      = (u16*)alloc((size_t)NROWS * 3072 * 2);     // [kPacked(1024) | v(2048)]
  u16* krope    = (u16*)alloc((size_t)NROWS * 64 * 2);
  u16* qrope    = (u16*)alloc((size_t)NROWS * 64 * 2);       // pre-scaled
  u16* vT       = (u16*)alloc((size_t)32 * 128 * T_ * 2);    // [bh][d][t]
  u16* aout     = (u16*)alloc((size_t)NROWS * DIM_ * 2);
  (void)in_sizes; (void)n_in; (void)out_size; (void)ws_size;

  const float SC2 = 0.12753139626374414f;   // 1/sqrt(128) * log2(e)

  hipLaunchKernelGGL(k_detect, dim3(1), dim3(64), 0, stream, (const u16*)cosp, flag, ticket);

  int n4 = NROWS * DIM_ / 4;
  hipLaunchKernelGGL(k_conv, dim3((n4 + 255) / 256), dim3(256), 0, stream, x, x_bf, n4, flag);

  // weight transposes into combined buffers (grid = (dstRows/64, srcRows/64))
  hipLaunchKernelGGL(k_transpose, dim3(8,  32), dim3(256), 0, stream, w_kv,    w_c1T,                        512,  2048, 64,  flag);
  hipLaunchKernelGGL(k_transpose, dim3(24, 32), dim3(256), 0, stream, w_qc,    w_c1T + (size_t)512 * 2048,   1536, 2048, 64,  flag);
  hipLaunchKernelGGL(k_transpose, dim3(1,  32), dim3(256), 0, stream, w_krope, w_c1T + (size_t)2048 * 2048,  64,   2048, 64,  flag);
  hipLaunchKernelGGL(k_transpose, dim3(1,  32), dim3(256), 0, stream, w_qrope, w_c1T + (size_t)2112 * 2048,  64,   2048, 64,  flag);
  hipLaunchKernelGGL(k_transpose, dim3(16, 8),  dim3(256), 0, stream, w_kdec,  w_kvdT,                       2048, 512,  128, flag);
  hipLaunchKernelGGL(k_transpose, dim3(32, 8),  dim3(256), 0, stream, w_vdec,  w_kvdT + (size_t)1024 * 512,  2048, 512,  64,  flag);
  hipLaunchKernelGGL(k_transpose, dim3(16, 24), dim3(256), 0, stream, w_qdec,  w_qdPT,                       2048, 1536, 128, flag);
  hipLaunchKernelGGL(k_transpose, dim3(32, 32), dim3(256), 0, stream, w_o,     w_oT,                         2048, 2048, 64,  flag);

  // G13: xc = x @ [w_kv | w_qc | w_krope | w_qrope]  (4096 x 2176, K=2048)
  hipLaunchKernelGGL(k_gemm, dim3(NROWS/128, 2176/128), dim3(256), 0, stream,
                     x_bf, DIM_, w_c1T, xc, 2176, NROWS, 2176, DIM_, 1.0f, (void*)nullptr, (const int*)nullptr);
  // G2: kvP = xc[:, :512] @ [w_kdecP | w_vdec]   (4096 x 3072, K=512)
  hipLaunchKernelGGL(k_gemm, dim3(NROWS/128, 3072/128), dim3(256), 0, stream,
                     xc, 2176, w_kvdT, kvP, 3072, NROWS, 3072, DC_, 1.0f, (void*)nullptr, (const int*)nullptr);
  // G4: qP = xc[:, 512:2048] @ w_qdecP   (4096 x 1024, K=1536), pre-scaled for softmax
  hipLaunchKernelGGL(k_gemm, dim3(NROWS/128, 1024/128), dim3(256), 0, stream,
                     xc + 512, 2176, w_qdPT, qP, 1024, NROWS, 1024, DCQ_, SC2, (void*)nullptr, (const int*)nullptr);
  // RoPE (q-part pre-scaled)
  hipLaunchKernelGGL(k_rope, dim3(NROWS * 128 / 256), dim3(256), 0, stream,
                     xc + 2048, cosp, sinp, flag, krope, qrope);
  // vT[bh][d][t]
  hipLaunchKernelGGL(k_vt, dim3(T_/64, 2, 32), dim3(256), 0, stream, kvP, vT);
  // attention (persistent, 512 worker blocks = 2/CU)
  hipLaunchKernelGGL(k_attn, dim3(512), dim3(256), 0, stream,
                     qP, kvP, vT, krope, qrope, aout, ticket);
  // G5: out = aout @ w_o  (writes d_out; dtype per flag)
  hipLaunchKernelGGL(k_gemm, dim3(NROWS/128, DIM_/128), dim3(256), 0, stream,
                     aout, DIM_, w_oT, (u16*)nullptr, DIM_, NROWS, DIM_, DIM_, 1.0f, d_out, (const int*)flag);
}

// Round 6
// 347.970 us; speedup vs baseline: 1.4284x; 1.2066x over previous
//
#include <hip/hip_runtime.h>
#include <stdint.h>
#include <math.h>

#define B_    2
#define T_    2048
#define DIM_  2048
#define H_    16
#define DC_   512
#define DCQ_  1536
#define NROWS (B_*T_)   // 4096
#define NITEMS 1024

typedef unsigned short u16;
typedef __attribute__((ext_vector_type(8))) __bf16 bf16x8;
typedef __attribute__((ext_vector_type(4))) float  f32x4;
typedef __attribute__((ext_vector_type(8))) unsigned short u16x8;
typedef __attribute__((ext_vector_type(4))) float  f4v;

__device__ __forceinline__ u16 f2bf(float f){
  unsigned u = __float_as_uint(f);
  u += 0x7FFFu + ((u >> 16) & 1u);   // RNE
  return (u16)(u >> 16);
}
__device__ __forceinline__ float bf2f(u16 h){ return __uint_as_float(((unsigned)h) << 16); }

__device__ __forceinline__ unsigned cvt_pk_bf16(float lo, float hi){
  unsigned r;
  asm("v_cvt_pk_bf16_f32 %0, %1, %2" : "=v"(r) : "v"(lo), "v"(hi));
  return r;
}

// async global->LDS, 16B per lane; LDS dest = wave-uniform base + lane*16.
__device__ __forceinline__ void gld_lds16(const void* g, void* l){
  auto gp = reinterpret_cast<__attribute__((address_space(1))) unsigned int*>(
      reinterpret_cast<uintptr_t>(g));
  auto lp = reinterpret_cast<__attribute__((address_space(3))) unsigned int*>(
      reinterpret_cast<uintptr_t>(l));
  __builtin_amdgcn_global_load_lds(gp, lp, 16, 0, 0);
}

__device__ __forceinline__ f32x4 mfma16(bf16x8 a, bf16x8 b, f32x4 c){
  return __builtin_amdgcn_mfma_f32_16x16x32_bf16(a, b, c, 0, 0, 0);
}

// ---------------- dtype detect + ticket reset
__global__ void k_detect(const u16* cosr, int* flag, int* ticket){
  if (threadIdx.x == 0){
    *flag = (cosr[0] == (u16)0x3F80u) ? 1 : 0;
    *ticket = 0;
  }
}

// ---------------- convert to bf16
__global__ void k_conv(const void* __restrict__ src, u16* __restrict__ dst, int n4, const int* flag){
  int id = blockIdx.x * 256 + threadIdx.x;
  if (id >= n4) return;
  if (*flag){
    reinterpret_cast<uint2*>(dst)[id] = reinterpret_cast<const uint2*>(src)[id];
  } else {
    f4v v = reinterpret_cast<const f4v*>(src)[id];
    unsigned lo = (unsigned)f2bf(v.x) | ((unsigned)f2bf(v.y) << 16);
    unsigned hi = (unsigned)f2bf(v.z) | ((unsigned)f2bf(v.w) << 16);
    reinterpret_cast<uint2*>(dst)[id] = make_uint2(lo, hi);
  }
}

// ---------------- transpose+convert to bf16 with optional column packing.
__global__ void k_transpose(const void* __restrict__ src, u16* __restrict__ dst,
                            int srcStride, int dstStride, int cblk, const int* flag){
  __shared__ u16 tile[64][72];
  const int r0 = blockIdx.y << 6, c0 = blockIdx.x * cblk;
  const int tid = threadIdx.x;
  const int f = *flag;
  #pragma unroll
  for (int i = 0; i < 2; ++i){
    int task = (i << 8) + tid;
    int r = task >> 3, c8 = (task & 7) << 3;
    if (f){
      const u16* p = (const u16*)src + (size_t)(r0 + r) * srcStride + c0 + c8;
      u16x8 v = *reinterpret_cast<const u16x8*>(p);
      #pragma unroll
      for (int j = 0; j < 8; ++j) tile[r][c8 + j] = v[j];
    } else {
      const float* p = (const float*)src + (size_t)(r0 + r) * srcStride + c0 + c8;
      f4v a = reinterpret_cast<const f4v*>(p)[0];
      f4v b = reinterpret_cast<const f4v*>(p)[1];
      tile[r][c8+0]=f2bf(a.x); tile[r][c8+1]=f2bf(a.y); tile[r][c8+2]=f2bf(a.z); tile[r][c8+3]=f2bf(a.w);
      tile[r][c8+4]=f2bf(b.x); tile[r][c8+5]=f2bf(b.y); tile[r][c8+6]=f2bf(b.z); tile[r][c8+7]=f2bf(b.w);
    }
  }
  __syncthreads();
  #pragma unroll
  for (int i = 0; i < 2; ++i){
    int task = (i << 8) + tid;
    int rr = task >> 3, cc8 = (task & 7) << 3;
    u16x8 v;
    #pragma unroll
    for (int j = 0; j < 8; ++j) v[j] = tile[cc8 + j][rr];
    *reinterpret_cast<u16x8*>(dst + (size_t)((blockIdx.x << 6) + rr) * dstStride + r0 + cc8) = v;
  }
}

// ---------------- build vT[bh][d][t] from kvP cols 1024 + h*128 + d
__global__ void k_vt(const u16* __restrict__ kvP, u16* __restrict__ vT){
  __shared__ u16 tile[64][72];
  const int t0 = blockIdx.x << 6, d0 = blockIdx.y << 6, bh = blockIdx.z;
  const int b = bh >> 4, h = bh & 15;
  const int tid = threadIdx.x;
  #pragma unroll
  for (int i = 0; i < 2; ++i){
    int task = (i << 8) + tid;
    int r = task >> 3, c8 = (task & 7) << 3;
    const u16* p = kvP + (size_t)(b * T_ + t0 + r) * 3072 + 1024 + h * 128 + d0 + c8;
    u16x8 v = *reinterpret_cast<const u16x8*>(p);
    #pragma unroll
    for (int j = 0; j < 8; ++j) tile[r][c8 + j] = v[j];
  }
  __syncthreads();
  #pragma unroll
  for (int i = 0; i < 2; ++i){
    int task = (i << 8) + tid;
    int rr = task >> 3, cc8 = (task & 7) << 3;
    u16x8 v;
    #pragma unroll
    for (int j = 0; j < 8; ++j) v[j] = tile[cc8 + j][rr];
    *reinterpret_cast<u16x8*>(vT + ((size_t)bh * 128 + d0 + rr) * T_ + t0 + cc8) = v;
  }
}

// ---------------- GEMM: C(MxN) = A(MxK, lda) * Bt(NxK row-major)  [bf16 in, fp32 acc]
__global__ __launch_bounds__(256) void k_gemm(const u16* __restrict__ A, int lda,
                                              const u16* __restrict__ Bt,
                                              u16* __restrict__ C, int ldc,
                                              int M, int N, int K, float oscale,
                                              void* outp, const int* flag){
  __shared__ alignas(16) u16 As[128 * 64];
  __shared__ alignas(16) u16 Bs[128 * 64];
  const int tid = threadIdx.x;
  const int wid = tid >> 6, lane = tid & 63;
  const int m0 = blockIdx.x << 7, n0 = blockIdx.y << 7;
  const int wr = wid >> 1, wc = wid & 1;
  const int l16 = lane & 15, lk = (lane >> 4) << 3;
  const int srow = tid >> 3, scol = (tid & 7) << 3;
  f32x4 acc[4][4] = {};
  const int nkt = K >> 6;
  for (int kt = 0; kt < nkt; ++kt){
    const int kb = kt << 6;
    #pragma unroll
    for (int i = 0; i < 4; ++i){
      int r = (i << 5) + srow;
      gld_lds16(A  + (size_t)(m0 + r) * lda + kb + scol, &As[(i << 11) + (wid << 9)]);
      gld_lds16(Bt + (size_t)(n0 + r) * K   + kb + scol, &Bs[(i << 11) + (wid << 9)]);
    }
    __syncthreads();
    #pragma unroll
    for (int ks = 0; ks < 2; ++ks){
      bf16x8 af[4], bfr[4];
      #pragma unroll
      for (int mi = 0; mi < 4; ++mi)
        af[mi] = *reinterpret_cast<const bf16x8*>(&As[((wr << 6) + (mi << 4) + l16) * 64 + (ks << 5) + lk]);
      #pragma unroll
      for (int ni = 0; ni < 4; ++ni)
        bfr[ni] = *reinterpret_cast<const bf16x8*>(&Bs[((wc << 6) + (ni << 4) + l16) * 64 + (ks << 5) + lk]);
      #pragma unroll
      for (int mi = 0; mi < 4; ++mi)
        #pragma unroll
        for (int ni = 0; ni < 4; ++ni)
          acc[mi][ni] = mfma16(af[mi], bfr[ni], acc[mi][ni]);
    }
    __syncthreads();
  }
  const int r4 = (lane >> 4) << 2;
  const int f = flag ? *flag : 1;
  #pragma unroll
  for (int mi = 0; mi < 4; ++mi){
    int row = m0 + (wr << 6) + (mi << 4) + r4;
    #pragma unroll
    for (int ni = 0; ni < 4; ++ni){
      int col = n0 + (wc << 6) + (ni << 4) + l16;
      #pragma unroll
      for (int j = 0; j < 4; ++j){
        float v = acc[mi][ni][j] * oscale;
        if (outp){
          if (f) ((u16*)outp)[(size_t)(row + j) * ldc + col] = f2bf(v);
          else   ((float*)outp)[(size_t)(row + j) * ldc + col] = v;
        } else {
          C[(size_t)(row + j) * ldc + col] = f2bf(v);
        }
      }
    }
  }
}

// ---------------- RoPE from xc cols 2048..2175 (stride 2176); q-part pre-scaled by 1/sqrt(D)*log2e
__global__ void k_rope(const u16* __restrict__ ropes, const void* __restrict__ cosp,
                       const void* __restrict__ sinp, const int* flag,
                       u16* __restrict__ krope, u16* __restrict__ qrope){
  int id = blockIdx.x * 256 + threadIdx.x;
  if (id >= NROWS * 128) return;
  int row = id >> 7, c = id & 127;
  int t = row & (T_ - 1);
  int d = c & 63, i = d & 31;
  float cs, sn;
  if (*flag){ cs = bf2f(((const u16*)cosp)[t * 32 + i]); sn = bf2f(((const u16*)sinp)[t * 32 + i]); }
  else      { cs = ((const float*)cosp)[t * 32 + i];     sn = ((const float*)sinp)[t * 32 + i]; }
  int base = c & 64;
  float t1 = bf2f(ropes[(size_t)row * 2176 + base + i]);
  float t2 = bf2f(ropes[(size_t)row * 2176 + base + 32 + i]);
  float v = (d < 32) ? (t1 * cs - t2 * sn) : (t2 * cs + t1 * sn);
  if (c >= 64) v *= 0.12753139626374414f;   // 1/sqrt(128) * log2(e), folded into q
  ((c < 64) ? krope : qrope)[(size_t)row * 64 + d] = f2bf(v);
}

// ---------------- causal flash attention, swapped-QK^T register softmax.
// Item = (qt, bh): 64 q-rows, 4 waves x 16 rows. KV tiles of 64, gload_lds double-buffer.
// LDS 64 KB: buffer b (32KB @ b*16384 u16): K [64][128], V [128][64] @ +8192.
// XOR-swizzled (col ^= (row&7)<<3) via pre-swizzled global sources. No P in LDS:
// S^T = mfma(K,Q) puts P[q=l16] lane-local; PV A-frags rebuilt via cvt_pk + shfl.
__global__ __launch_bounds__(256, 2) void k_attn(const u16* __restrict__ qP,
                                                 const u16* __restrict__ kvP,
                                                 const u16* __restrict__ vT,
                                                 const u16* __restrict__ krope,
                                                 const u16* __restrict__ qrope,
                                                 u16* __restrict__ aout,
                                                 int* __restrict__ ticket){
  __shared__ alignas(16) u16 smem[32768];   // 64 KB exactly -> 2 blocks/CU
  const int tid = threadIdx.x, wid = tid >> 6, lane = tid & 63;
  const int l16 = lane & 15, g = lane >> 4;
  const int lk = g << 3, r4 = g << 2;
  const int sw8 = (l16 & 7) << 3;

  while (true){
    if (tid == 0) *(int*)&smem[0] = atomicAdd(ticket, 1);
    __syncthreads();                        // broadcast visible
    const int it = *(const int*)&smem[0];
    __syncthreads();                        // read before staging overwrites
    if (it >= NITEMS) break;
    const int qt = 31 - (it >> 5);          // heavy-first
    const int bh = it & 31, b = bh >> 4, h = bh & 15;
    const int q0 = qt << 6;
    const size_t bT = (size_t)b * T_;
    const u16* kvPb = kvP + bT * 3072 + (h << 6);
    const u16* krb  = krope + bT * 64;
    const u16* vTb  = vT + (size_t)bh * 128 * T_;
    const int qlo = q0 + (wid << 4);
    const int nkv = qt + 1;

    auto STAGE = [&](int buf, int k0){
      const int base = buf << 14;
      #pragma unroll
      for (int r = 0; r < 8; ++r){
        int c = (r << 8) + tid;
        const u16* src;
        if (r < 4){
          int row = c >> 4, cc = c & 15;
          int ccx = (cc & 8) | ((cc & 7) ^ (row & 7));
          int col0 = ccx << 3;
          src = (col0 < 64) ? (kvPb + (size_t)(k0 + row) * 3072 + col0)
                            : (krb  + (size_t)(k0 + row) * 64 + (col0 - 64));
        } else {
          int cv = c - 1024;
          int row = cv >> 3, cc = cv & 7;
          int ccx = cc ^ (row & 7);
          src = vTb + (size_t)row * T_ + k0 + (ccx << 3);
        }
        gld_lds16(src, &smem[base + (((r << 8) + (wid << 6)) << 3)]);
      }
    };

    // Q fragments (pre-scaled by 1/sqrt(D)*log2e upstream); lane l16 = q-row qlo+l16
    bf16x8 qf[4];
    {
      size_t grow = bT + qlo + l16;
      #pragma unroll
      for (int ks = 0; ks < 4; ++ks){
        int d = (ks << 5) + lk;
        const u16* src = (ks < 2) ? (qP + grow * 1024 + (h << 6) + d)
                                  : (qrope + grow * 64 + (d - 64));
        qf[ks] = *reinterpret_cast<const bf16x8*>(src);
      }
    }
    f32x4 o[8] = {};
    float m = -3e38f, l = 0.f;

    STAGE(0, 0);
    __syncthreads();                        // tile 0 resident
    int cur = 0;

    for (int kv = 0; kv < nkv; ++kv){
      const int k0 = kv << 6;
      if (kv + 1 < nkv) STAGE(cur ^ 1, (kv + 1) << 6);   // prefetch next tile
      const int kb = cur << 14;
      // ---- S^T = K Q^T : s[n][j] = S[k0 + 16n + r4 + j][q = qlo + l16]
      f32x4 s[4] = {};
      #pragma unroll
      for (int ks = 0; ks < 4; ++ks){
        int colsw = ((ks << 5) + lk) ^ sw8;
        #pragma unroll
        for (int n = 0; n < 4; ++n){
          bf16x8 kf = *reinterpret_cast<const bf16x8*>(&smem[kb + ((n << 4) + l16) * 128 + colsw]);
          s[n] = mfma16(kf, qf[ks], s[n]);
        }
      }
      // ---- causal mask: only the diagonal tile
      if (k0 == q0){
        const int tq = qlo + l16;
        #pragma unroll
        for (int n = 0; n < 4; ++n)
          #pragma unroll
          for (int j = 0; j < 4; ++j)
            s[n][j] = (k0 + (n << 4) + r4 + j <= tq) ? s[n][j] : -3e38f;
      }
      // ---- row max (per-lane 16 values + groups via xor16/xor32)
      float mx;
      {
        float a0 = fmaxf(fmaxf(s[0][0], s[0][1]), fmaxf(s[0][2], s[0][3]));
        float a1 = fmaxf(fmaxf(s[1][0], s[1][1]), fmaxf(s[1][2], s[1][3]));
        float a2 = fmaxf(fmaxf(s[2][0], s[2][1]), fmaxf(s[2][2], s[2][3]));
        float a3 = fmaxf(fmaxf(s[3][0], s[3][1]), fmaxf(s[3][2], s[3][3]));
        mx = fmaxf(fmaxf(a0, a1), fmaxf(a2, a3));
        mx = fmaxf(mx, __shfl_xor(mx, 16));
        mx = fmaxf(mx, __shfl_xor(mx, 32));
      }
      // ---- deferred rescale (wave-uniform)
      if (__ballot(mx > m + 8.f)){
        float mnew = fmaxf(m, mx);
        float alpha = exp2f(m - mnew);
        m = mnew; l *= alpha;
        #pragma unroll
        for (int j = 0; j < 4; ++j){
          float av = __shfl(alpha, r4 + j);   // alpha of o-row r4+j
          #pragma unroll
          for (int db = 0; db < 8; ++db) o[db][j] *= av;
        }
      }
      // ---- P = exp2(s - m), pack bf16 pairs, row sum
      unsigned w[4][2];
      float rs = 0.f;
      #pragma unroll
      for (int n = 0; n < 4; ++n)
        #pragma unroll
        for (int jh = 0; jh < 2; ++jh){
          float p0 = exp2f(s[n][2*jh]     - m);
          float p1 = exp2f(s[n][2*jh + 1] - m);
          rs += p0 + p1;
          w[n][jh] = cvt_pk_bf16(p0, p1);   // k = 16n + 4g + {2jh, 2jh+1}
        }
      rs += __shfl_xor(rs, 16);
      rs += __shfl_xor(rs, 32);
      l += rs;
      // ---- rebuild PV A-frags: pa[ks2] holds P[q=l16][k = 32ks2+8g+0..7]
      const int srcA = l16 + ((g & 1) << 5);   // gsrc = 2*(g&1)
      const int srcB = srcA + 16;              // gsrc = 2*(g&1)+1
      const bool hi = (g >= 2);
      bf16x8 pa[2];
      #pragma unroll
      for (int ks2 = 0; ks2 < 2; ++ks2){
        unsigned a0 = __shfl((int)w[2*ks2][0],     srcA);
        unsigned b0 = __shfl((int)w[2*ks2 + 1][0], srcA);
        unsigned a1 = __shfl((int)w[2*ks2][1],     srcA);
        unsigned b1 = __shfl((int)w[2*ks2 + 1][1], srcA);
        unsigned a2 = __shfl((int)w[2*ks2][0],     srcB);
        unsigned b2 = __shfl((int)w[2*ks2 + 1][0], srcB);
        unsigned a3 = __shfl((int)w[2*ks2][1],     srcB);
        unsigned b3 = __shfl((int)w[2*ks2 + 1][1], srcB);
        union { unsigned u[4]; bf16x8 v; } pk;
        pk.u[0] = hi ? b0 : a0;
        pk.u[1] = hi ? b1 : a1;
        pk.u[2] = hi ? b2 : a2;
        pk.u[3] = hi ? b3 : a3;
        pa[ks2] = pk.v;
      }
      // ---- O += P V
      #pragma unroll
      for (int ks2 = 0; ks2 < 2; ++ks2){
        int colsw = ((ks2 << 5) + lk) ^ sw8;
        #pragma unroll
        for (int db = 0; db < 8; ++db){
          bf16x8 vb = *reinterpret_cast<const bf16x8*>(&smem[kb + 8192 + ((db << 4) + l16) * 64 + colsw]);
          o[db] = mfma16(pa[ks2], vb, o[db]);
        }
      }
      __syncthreads();                      // drains prefetch; reads done before reuse
      cur ^= 1;
    }
    // ---- epilogue: o[db][j] = O[q = qlo + r4 + j][d = 16db + l16]
    #pragma unroll
    for (int j = 0; j < 4; ++j){
      float lv = __shfl(l, r4 + j);
      float rinv = 1.f / lv;
      const int tq = qlo + r4 + j;
      u16* dst = aout + (bT + tq) * 2048 + (h << 7) + l16;
      #pragma unroll
      for (int db = 0; db < 8; ++db)
        dst[db << 4] = f2bf(o[db][j] * rinv);
    }
  }
}

extern "C" void kernel_launch(void* const* d_in, const int* in_sizes, int n_in,
                              void* d_out, int out_size, void* d_ws, size_t ws_size,
                              hipStream_t stream){
  const void* x       = d_in[0];
  const void* cosp    = d_in[1];
  const void* sinp    = d_in[2];
  const void* w_kv    = d_in[3];
  const void* w_kdec  = d_in[4];
  const void* w_vdec  = d_in[5];
  const void* w_qc    = d_in[6];
  const void* w_qdec  = d_in[7];
  const void* w_krope = d_in[8];
  const void* w_qrope = d_in[9];
  const void* w_o     = d_in[10];

  char* ws = (char*)d_ws;
  size_t off = 0;
  auto alloc = [&](size_t bytes){ void* p = ws + off; off += (bytes + 255) & ~(size_t)255; return p; };
  int* flag     = (int*)alloc(256);
  int* ticket   = (int*)alloc(256);
  u16* x_bf     = (u16*)alloc((size_t)NROWS * DIM_ * 2);
  u16* w_c1T    = (u16*)alloc((size_t)2176 * DIM_ * 2);      // [kvT(512); qcT(1536); kropeT(64); qropeT(64)] x 2048
  u16* w_kvdT   = (u16*)alloc((size_t)3072 * DC_ * 2);       // [kdecPackedT(1024); vdecT(2048)] x 512
  u16* w_qdPT   = (u16*)alloc((size_t)1024 * DCQ_ * 2);      // packed qdecT (1024 x 1536)
  u16* w_oT     = (u16*)alloc((size_t)DIM_ * DIM_ * 2);
  u16* xc       = (u16*)alloc((size_t)NROWS * 2176 * 2);     // [c_kv(512) | c_q(1536) | ropes(128)]
  u16* qP       = (u16*)alloc((size_t)NROWS * 1024 * 2);     // packed q decode (pre-scaled)
  u16* kvP      = (u16*)alloc((size_t)NROWS * 3072 * 2);     // [kPacked(1024) | v(2048)]
  u16* krope    = (u16*)alloc((size_t)NROWS * 64 * 2);
  u16* qrope    = (u16*)alloc((size_t)NROWS * 64 * 2);       // pre-scaled
  u16* vT       = (u16*)alloc((size_t)32 * 128 * T_ * 2);    // [bh][d][t]
  u16* aout     = (u16*)alloc((size_t)NROWS * DIM_ * 2);
  (void)in_sizes; (void)n_in; (void)out_size; (void)ws_size;

  const float SC2 = 0.12753139626374414f;   // 1/sqrt(128) * log2(e)

  hipLaunchKernelGGL(k_detect, dim3(1), dim3(64), 0, stream, (const u16*)cosp, flag, ticket);

  int n4 = NROWS * DIM_ / 4;
  hipLaunchKernelGGL(k_conv, dim3((n4 + 255) / 256), dim3(256), 0, stream, x, x_bf, n4, flag);

  // weight transposes into combined buffers (grid = (dstRows/64, srcRows/64))
  hipLaunchKernelGGL(k_transpose, dim3(8,  32), dim3(256), 0, stream, w_kv,    w_c1T,                        512,  2048, 64,  flag);
  hipLaunchKernelGGL(k_transpose, dim3(24, 32), dim3(256), 0, stream, w_qc,    w_c1T + (size_t)512 * 2048,   1536, 2048, 64,  flag);
  hipLaunchKernelGGL(k_transpose, dim3(1,  32), dim3(256), 0, stream, w_krope, w_c1T + (size_t)2048 * 2048,  64,   2048, 64,  flag);
  hipLaunchKernelGGL(k_transpose, dim3(1,  32), dim3(256), 0, stream, w_qrope, w_c1T + (size_t)2112 * 2048,  64,   2048, 64,  flag);
  hipLaunchKernelGGL(k_transpose, dim3(16, 8),  dim3(256), 0, stream, w_kdec,  w_kvdT,                       2048, 512,  128, flag);
  hipLaunchKernelGGL(k_transpose, dim3(32, 8),  dim3(256), 0, stream, w_vdec,  w_kvdT + (size_t)1024 * 512,  2048, 512,  64,  flag);
  hipLaunchKernelGGL(k_transpose, dim3(16, 24), dim3(256), 0, stream, w_qdec,  w_qdPT,                       2048, 1536, 128, flag);
  hipLaunchKernelGGL(k_transpose, dim3(32, 32), dim3(256), 0, stream, w_o,     w_oT,                         2048, 2048, 64,  flag);

  // G13: xc = x @ [w_kv | w_qc | w_krope | w_qrope]  (4096 x 2176, K=2048)
  hipLaunchKernelGGL(k_gemm, dim3(NROWS/128, 2176/128), dim3(256), 0, stream,
                     x_bf, DIM_, w_c1T, xc, 2176, NROWS, 2176, DIM_, 1.0f, (void*)nullptr, (const int*)nullptr);
  // G2: kvP = xc[:, :512] @ [w_kdecP | w_vdec]   (4096 x 3072, K=512)
  hipLaunchKernelGGL(k_gemm, dim3(NROWS/128, 3072/128), dim3(256), 0, stream,
                     xc, 2176, w_kvdT, kvP, 3072, NROWS, 3072, DC_, 1.0f, (void*)nullptr, (const int*)nullptr);
  // G4: qP = xc[:, 512:2048] @ w_qdecP   (4096 x 1024, K=1536), pre-scaled for softmax
  hipLaunchKernelGGL(k_gemm, dim3(NROWS/128, 1024/128), dim3(256), 0, stream,
                     xc + 512, 2176, w_qdPT, qP, 1024, NROWS, 1024, DCQ_, SC2, (void*)nullptr, (const int*)nullptr);
  // RoPE (q-part pre-scaled)
  hipLaunchKernelGGL(k_rope, dim3(NROWS * 128 / 256), dim3(256), 0, stream,
                     xc + 2048, cosp, sinp, flag, krope, qrope);
  // vT[bh][d][t]
  hipLaunchKernelGGL(k_vt, dim3(T_/64, 2, 32), dim3(256), 0, stream, kvP, vT);
  // attention (persistent, 512 worker blocks = 2/CU, 1024 items)
  hipLaunchKernelGGL(k_attn, dim3(512), dim3(256), 0, stream,
                     qP, kvP, vT, krope, qrope, aout, ticket);
  // G5: out = aout @ w_o  (writes d_out; dtype per flag)
  hipLaunchKernelGGL(k_gemm, dim3(NROWS/128, DIM_/128), dim3(256), 0, stream,
                     aout, DIM_, w_oT, (u16*)nullptr, DIM_, NROWS, DIM_, DIM_, 1.0f, d_out, (const int*)flag);
}

// Round 7
// 328.085 us; speedup vs baseline: 1.5150x; 1.0606x over previous
//
#include <hip/hip_runtime.h>
#include <stdint.h>
#include <math.h>

#define B_    2
#define T_    2048
#define DIM_  2048
#define H_    16
#define DC_   512
#define DCQ_  1536
#define NROWS (B_*T_)   // 4096
#define NITEMS 1024

typedef unsigned short u16;
typedef __attribute__((ext_vector_type(8))) __bf16 bf16x8;
typedef __attribute__((ext_vector_type(4))) float  f32x4;
typedef __attribute__((ext_vector_type(8))) unsigned short u16x8;
typedef __attribute__((ext_vector_type(4))) float  f4v;

__device__ __forceinline__ u16 f2bf(float f){
  unsigned u = __float_as_uint(f);
  u += 0x7FFFu + ((u >> 16) & 1u);   // RNE
  return (u16)(u >> 16);
}
__device__ __forceinline__ float bf2f(u16 h){ return __uint_as_float(((unsigned)h) << 16); }

__device__ __forceinline__ unsigned cvt_pk_bf16(float lo, float hi){
  unsigned r;
  asm("v_cvt_pk_bf16_f32 %0, %1, %2" : "=v"(r) : "v"(lo), "v"(hi));
  return r;
}

// async global->LDS, 16B per lane; LDS dest = wave-uniform base + lane*16.
__device__ __forceinline__ void gld_lds16(const void* g, void* l){
  auto gp = reinterpret_cast<__attribute__((address_space(1))) unsigned int*>(
      reinterpret_cast<uintptr_t>(g));
  auto lp = reinterpret_cast<__attribute__((address_space(3))) unsigned int*>(
      reinterpret_cast<uintptr_t>(l));
  __builtin_amdgcn_global_load_lds(gp, lp, 16, 0, 0);
}

__device__ __forceinline__ f32x4 mfma16(bf16x8 a, bf16x8 b, f32x4 c){
  return __builtin_amdgcn_mfma_f32_16x16x32_bf16(a, b, c, 0, 0, 0);
}

__device__ __forceinline__ void vmwait0(){ asm volatile("s_waitcnt vmcnt(0)" ::: "memory"); }
__device__ __forceinline__ void barr(){ asm volatile("s_barrier" ::: "memory"); }

// ---------------- dtype detect + ticket reset
__global__ void k_detect(const u16* cosr, int* flag, int* ticket){
  if (threadIdx.x == 0){
    *flag = (cosr[0] == (u16)0x3F80u) ? 1 : 0;
    *ticket = 0;
  }
}

// ---------------- convert to bf16
__global__ void k_conv(const void* __restrict__ src, u16* __restrict__ dst, int n4, const int* flag){
  int id = blockIdx.x * 256 + threadIdx.x;
  if (id >= n4) return;
  if (*flag){
    reinterpret_cast<uint2*>(dst)[id] = reinterpret_cast<const uint2*>(src)[id];
  } else {
    f4v v = reinterpret_cast<const f4v*>(src)[id];
    unsigned lo = (unsigned)f2bf(v.x) | ((unsigned)f2bf(v.y) << 16);
    unsigned hi = (unsigned)f2bf(v.z) | ((unsigned)f2bf(v.w) << 16);
    reinterpret_cast<uint2*>(dst)[id] = make_uint2(lo, hi);
  }
}

// ---------------- transpose+convert to bf16 with optional column packing.
__global__ void k_transpose(const void* __restrict__ src, u16* __restrict__ dst,
                            int srcStride, int dstStride, int cblk, const int* flag){
  __shared__ u16 tile[64][72];
  const int r0 = blockIdx.y << 6, c0 = blockIdx.x * cblk;
  const int tid = threadIdx.x;
  const int f = *flag;
  #pragma unroll
  for (int i = 0; i < 2; ++i){
    int task = (i << 8) + tid;
    int r = task >> 3, c8 = (task & 7) << 3;
    if (f){
      const u16* p = (const u16*)src + (size_t)(r0 + r) * srcStride + c0 + c8;
      u16x8 v = *reinterpret_cast<const u16x8*>(p);
      #pragma unroll
      for (int j = 0; j < 8; ++j) tile[r][c8 + j] = v[j];
    } else {
      const float* p = (const float*)src + (size_t)(r0 + r) * srcStride + c0 + c8;
      f4v a = reinterpret_cast<const f4v*>(p)[0];
      f4v b = reinterpret_cast<const f4v*>(p)[1];
      tile[r][c8+0]=f2bf(a.x); tile[r][c8+1]=f2bf(a.y); tile[r][c8+2]=f2bf(a.z); tile[r][c8+3]=f2bf(a.w);
      tile[r][c8+4]=f2bf(b.x); tile[r][c8+5]=f2bf(b.y); tile[r][c8+6]=f2bf(b.z); tile[r][c8+7]=f2bf(b.w);
    }
  }
  __syncthreads();
  #pragma unroll
  for (int i = 0; i < 2; ++i){
    int task = (i << 8) + tid;
    int rr = task >> 3, cc8 = (task & 7) << 3;
    u16x8 v;
    #pragma unroll
    for (int j = 0; j < 8; ++j) v[j] = tile[cc8 + j][rr];
    *reinterpret_cast<u16x8*>(dst + (size_t)((blockIdx.x << 6) + rr) * dstStride + r0 + cc8) = v;
  }
}

// ---------------- build vT[bh][d][t] from kvP cols 1024 + h*128 + d
__global__ void k_vt(const u16* __restrict__ kvP, u16* __restrict__ vT){
  __shared__ u16 tile[64][72];
  const int t0 = blockIdx.x << 6, d0 = blockIdx.y << 6, bh = blockIdx.z;
  const int b = bh >> 4, h = bh & 15;
  const int tid = threadIdx.x;
  #pragma unroll
  for (int i = 0; i < 2; ++i){
    int task = (i << 8) + tid;
    int r = task >> 3, c8 = (task & 7) << 3;
    const u16* p = kvP + (size_t)(b * T_ + t0 + r) * 3072 + 1024 + h * 128 + d0 + c8;
    u16x8 v = *reinterpret_cast<const u16x8*>(p);
    #pragma unroll
    for (int j = 0; j < 8; ++j) tile[r][c8 + j] = v[j];
  }
  __syncthreads();
  #pragma unroll
  for (int i = 0; i < 2; ++i){
    int task = (i << 8) + tid;
    int rr = task >> 3, cc8 = (task & 7) << 3;
    u16x8 v;
    #pragma unroll
    for (int j = 0; j < 8; ++j) v[j] = tile[cc8 + j][rr];
    *reinterpret_cast<u16x8*>(vT + ((size_t)bh * 128 + d0 + rr) * T_ + t0 + cc8) = v;
  }
}

// ---------------- 256x256 8-phase GEMM (2 groups selectable by blockIdx.y).
// C(MxN) = A(MxK, lda) * Bt(NxK row-major), bf16 in, fp32 acc. M%256==0, N%256==0, K%64==0.
// 512 thr = 8 waves (2M x 4N), 128x64 per wave. LDS 128KB: 2 buffers x 4 half-tiles [128][64],
// st_16x32 swizzle (byte ^= ((byte>>9)&1)<<5) via inverse-swizzled global_load_lds sources.
// Per K-tile: stage kt+1 at phase0; 4 phases {ds_read, barrier, setprio+16 MFMA, barrier};
// vmcnt(0) only at tile boundary (loads issued 4 phases earlier -> latency covered).
#define MMQ(MH, NH, BFR) do{ \
  __builtin_amdgcn_s_setprio(1); \
  _Pragma("unroll") for (int ks = 0; ks < 2; ++ks) \
    _Pragma("unroll") for (int mi = 0; mi < 4; ++mi) \
      _Pragma("unroll") for (int ni = 0; ni < 2; ++ni) \
        acc[(MH)*4+mi][(NH)*2+ni] = mfma16(af[ks][mi], BFR[ks][ni], acc[(MH)*4+mi][(NH)*2+ni]); \
  __builtin_amdgcn_s_setprio(0); \
}while(0)

#define LDA(MH) do{ \
  _Pragma("unroll") for (int ks = 0; ks < 2; ++ks) \
    _Pragma("unroll") for (int mi = 0; mi < 4; ++mi){ \
      int Lb = (((MH)*64 + mi*16 + l16) << 7) + (ks << 6) + (g << 4); \
      Lb ^= ((Lb >> 9) & 1) << 5; \
      af[ks][mi] = *reinterpret_cast<const bf16x8*>(&lds[buf*32768 + wm*8192 + (Lb >> 1)]); \
    } \
}while(0)

#define LDB(DST, NH) do{ \
  _Pragma("unroll") for (int ks = 0; ks < 2; ++ks) \
    _Pragma("unroll") for (int ni = 0; ni < 2; ++ni){ \
      int Lb = ((((wn & 1) * 64) + (NH)*32 + ni*16 + l16) << 7) + (ks << 6) + (g << 4); \
      Lb ^= ((Lb >> 9) & 1) << 5; \
      DST[ks][ni] = *reinterpret_cast<const bf16x8*>(&lds[buf*32768 + 16384 + (wn >> 1)*8192 + (Lb >> 1)]); \
    } \
}while(0)

__global__ __launch_bounds__(512, 2) void k_gemm256(
    const u16* __restrict__ A0, int lda0, const u16* __restrict__ Bt0, int K0,
    u16* __restrict__ C0, int ldc0, float os0,
    const u16* __restrict__ A1, int lda1, const u16* __restrict__ Bt1, int K1,
    u16* __restrict__ C1, int ldc1, float os1,
    int ysplit, void* outp, const int* flag){
  __shared__ alignas(16) u16 lds[65536];   // 128 KB
  const int tid = threadIdx.x;
  const int wid = tid >> 6, lane = tid & 63;
  const int wm = wid >> 2, wn = wid & 3;
  const int l16 = lane & 15, g = lane >> 4;
  int by = blockIdx.y;
  const u16 *A, *Bt; u16* C; int lda, K, ldc; float oscale;
  if (by < ysplit){ A = A0; lda = lda0; Bt = Bt0; K = K0; C = C0; ldc = ldc0; oscale = os0; }
  else { by -= ysplit; A = A1; lda = lda1; Bt = Bt1; K = K1; C = C1; ldc = ldc1; oscale = os1; }
  const int m0 = blockIdx.x << 8, n0 = by << 8;
  const size_t Kz = (size_t)K;
  const int nkt = K >> 6;

  auto STAGE = [&](int kt, int bufn){
    const int kb = kt << 6;
    #pragma unroll
    for (int q = 0; q < 8; ++q){
      const int ht = q >> 1, ch = q & 1;
      const int Lb = ((ch * 8 + wid) << 10) + (lane << 4);   // byte within half-tile
      const int row = Lb >> 7;
      const int colb = (Lb & 127) ^ (((Lb >> 9) & 1) << 5);  // inverse-swizzled source
      const u16* src;
      if (ht < 2) src = A  + (size_t)(m0 + ht * 128 + row) * lda + kb + (colb >> 1);
      else        src = Bt + (size_t)(n0 + (ht - 2) * 128 + row) * Kz + kb + (colb >> 1);
      gld_lds16(src, &lds[bufn * 32768 + ht * 8192 + ((ch * 8 + wid) << 9)]);
    }
  };

  f32x4 acc[8][4] = {};
  bf16x8 af[2][4], bf0[2][2], bf1[2][2];

  STAGE(0, 0);
  vmwait0();
  barr();
  int buf = 0;

  for (int kt = 0; kt < nkt; ++kt){
    // phase 0: stage kt+1, read A[mh0] + B[nh0], compute (mh0,nh0)
    if (kt + 1 < nkt) STAGE(kt + 1, buf ^ 1);
    LDA(0);
    LDB(bf0, 0);
    barr();
    MMQ(0, 0, bf0);
    barr();
    // phase 1: read B[nh1], compute (mh0,nh1)
    LDB(bf1, 1);
    barr();
    MMQ(0, 1, bf1);
    barr();
    // phase 2: read A[mh1], compute (mh1,nh0)
    LDA(1);
    barr();
    MMQ(1, 0, bf0);
    barr();
    // phase 3: compute (mh1,nh1), then drain prefetch
    barr();
    MMQ(1, 1, bf1);
    vmwait0();
    barr();
    buf ^= 1;
  }

  const int r4 = g << 2;
  const int f = flag ? *flag : 1;
  #pragma unroll
  for (int mi8 = 0; mi8 < 8; ++mi8){
    int row = m0 + wm * 128 + mi8 * 16 + r4;
    #pragma unroll
    for (int ni4 = 0; ni4 < 4; ++ni4){
      int col = n0 + wn * 64 + ni4 * 16 + l16;
      #pragma unroll
      for (int j = 0; j < 4; ++j){
        float v = acc[mi8][ni4][j] * oscale;
        if (outp){
          if (f) ((u16*)outp)[(size_t)(row + j) * ldc + col] = f2bf(v);
          else   ((float*)outp)[(size_t)(row + j) * ldc + col] = v;
        } else {
          C[(size_t)(row + j) * ldc + col] = f2bf(v);
        }
      }
    }
  }
}

// ---------------- RoPE from xc cols 2048..2175 (stride 2304); q-part pre-scaled by 1/sqrt(D)*log2e
__global__ void k_rope(const u16* __restrict__ ropes, const void* __restrict__ cosp,
                       const void* __restrict__ sinp, const int* flag,
                       u16* __restrict__ krope, u16* __restrict__ qrope){
  int id = blockIdx.x * 256 + threadIdx.x;
  if (id >= NROWS * 128) return;
  int row = id >> 7, c = id & 127;
  int t = row & (T_ - 1);
  int d = c & 63, i = d & 31;
  float cs, sn;
  if (*flag){ cs = bf2f(((const u16*)cosp)[t * 32 + i]); sn = bf2f(((const u16*)sinp)[t * 32 + i]); }
  else      { cs = ((const float*)cosp)[t * 32 + i];     sn = ((const float*)sinp)[t * 32 + i]; }
  int base = c & 64;
  float t1 = bf2f(ropes[(size_t)row * 2304 + base + i]);
  float t2 = bf2f(ropes[(size_t)row * 2304 + base + 32 + i]);
  float v = (d < 32) ? (t1 * cs - t2 * sn) : (t2 * cs + t1 * sn);
  if (c >= 64) v *= 0.12753139626374414f;   // 1/sqrt(128) * log2(e), folded into q
  ((c < 64) ? krope : qrope)[(size_t)row * 64 + d] = f2bf(v);
}

// ---------------- causal flash attention, swapped-QK^T register softmax (round-6, unchanged).
__global__ __launch_bounds__(256, 2) void k_attn(const u16* __restrict__ qP,
                                                 const u16* __restrict__ kvP,
                                                 const u16* __restrict__ vT,
                                                 const u16* __restrict__ krope,
                                                 const u16* __restrict__ qrope,
                                                 u16* __restrict__ aout,
                                                 int* __restrict__ ticket){
  __shared__ alignas(16) u16 smem[32768];   // 64 KB -> 2 blocks/CU
  const int tid = threadIdx.x, wid = tid >> 6, lane = tid & 63;
  const int l16 = lane & 15, g = lane >> 4;
  const int lk = g << 3, r4 = g << 2;
  const int sw8 = (l16 & 7) << 3;

  while (true){
    if (tid == 0) *(int*)&smem[0] = atomicAdd(ticket, 1);
    __syncthreads();
    const int it = *(const int*)&smem[0];
    __syncthreads();
    if (it >= NITEMS) break;
    const int qt = 31 - (it >> 5);          // heavy-first
    const int bh = it & 31, b = bh >> 4, h = bh & 15;
    const int q0 = qt << 6;
    const size_t bT = (size_t)b * T_;
    const u16* kvPb = kvP + bT * 3072 + (h << 6);
    const u16* krb  = krope + bT * 64;
    const u16* vTb  = vT + (size_t)bh * 128 * T_;
    const int qlo = q0 + (wid << 4);
    const int nkv = qt + 1;

    auto STAGE = [&](int buf, int k0){
      const int base = buf << 14;
      #pragma unroll
      for (int r = 0; r < 8; ++r){
        int c = (r << 8) + tid;
        const u16* src;
        if (r < 4){
          int row = c >> 4, cc = c & 15;
          int ccx = (cc & 8) | ((cc & 7) ^ (row & 7));
          int col0 = ccx << 3;
          src = (col0 < 64) ? (kvPb + (size_t)(k0 + row) * 3072 + col0)
                            : (krb  + (size_t)(k0 + row) * 64 + (col0 - 64));
        } else {
          int cv = c - 1024;
          int row = cv >> 3, cc = cv & 7;
          int ccx = cc ^ (row & 7);
          src = vTb + (size_t)row * T_ + k0 + (ccx << 3);
        }
        gld_lds16(src, &smem[base + (((r << 8) + (wid << 6)) << 3)]);
      }
    };

    bf16x8 qf[4];
    {
      size_t grow = bT + qlo + l16;
      #pragma unroll
      for (int ks = 0; ks < 4; ++ks){
        int d = (ks << 5) + lk;
        const u16* src = (ks < 2) ? (qP + grow * 1024 + (h << 6) + d)
                                  : (qrope + grow * 64 + (d - 64));
        qf[ks] = *reinterpret_cast<const bf16x8*>(src);
      }
    }
    f32x4 o[8] = {};
    float m = -3e38f, l = 0.f;

    STAGE(0, 0);
    __syncthreads();
    int cur = 0;

    for (int kv = 0; kv < nkv; ++kv){
      const int k0 = kv << 6;
      if (kv + 1 < nkv) STAGE(cur ^ 1, (kv + 1) << 6);
      const int kb = cur << 14;
      f32x4 s[4] = {};
      #pragma unroll
      for (int ks = 0; ks < 4; ++ks){
        int colsw = ((ks << 5) + lk) ^ sw8;
        #pragma unroll
        for (int n = 0; n < 4; ++n){
          bf16x8 kf = *reinterpret_cast<const bf16x8*>(&smem[kb + ((n << 4) + l16) * 128 + colsw]);
          s[n] = mfma16(kf, qf[ks], s[n]);
        }
      }
      if (k0 == q0){
        const int tq = qlo + l16;
        #pragma unroll
        for (int n = 0; n < 4; ++n)
          #pragma unroll
          for (int j = 0; j < 4; ++j)
            s[n][j] = (k0 + (n << 4) + r4 + j <= tq) ? s[n][j] : -3e38f;
      }
      float mx;
      {
        float a0 = fmaxf(fmaxf(s[0][0], s[0][1]), fmaxf(s[0][2], s[0][3]));
        float a1 = fmaxf(fmaxf(s[1][0], s[1][1]), fmaxf(s[1][2], s[1][3]));
        float a2 = fmaxf(fmaxf(s[2][0], s[2][1]), fmaxf(s[2][2], s[2][3]));
        float a3 = fmaxf(fmaxf(s[3][0], s[3][1]), fmaxf(s[3][2], s[3][3]));
        mx = fmaxf(fmaxf(a0, a1), fmaxf(a2, a3));
        mx = fmaxf(mx, __shfl_xor(mx, 16));
        mx = fmaxf(mx, __shfl_xor(mx, 32));
      }
      if (__ballot(mx > m + 8.f)){
        float mnew = fmaxf(m, mx);
        float alpha = exp2f(m - mnew);
        m = mnew; l *= alpha;
        #pragma unroll
        for (int j = 0; j < 4; ++j){
          float av = __shfl(alpha, r4 + j);
          #pragma unroll
          for (int db = 0; db < 8; ++db) o[db][j] *= av;
        }
      }
      unsigned w[4][2];
      float rs = 0.f;
      #pragma unroll
      for (int n = 0; n < 4; ++n)
        #pragma unroll
        for (int jh = 0; jh < 2; ++jh){
          float p0 = exp2f(s[n][2*jh]     - m);
          float p1 = exp2f(s[n][2*jh + 1] - m);
          rs += p0 + p1;
          w[n][jh] = cvt_pk_bf16(p0, p1);
        }
      rs += __shfl_xor(rs, 16);
      rs += __shfl_xor(rs, 32);
      l += rs;
      const int srcA = l16 + ((g & 1) << 5);
      const int srcB = srcA + 16;
      const bool hi = (g >= 2);
      bf16x8 pa[2];
      #pragma unroll
      for (int ks2 = 0; ks2 < 2; ++ks2){
        unsigned a0 = __shfl((int)w[2*ks2][0],     srcA);
        unsigned b0 = __shfl((int)w[2*ks2 + 1][0], srcA);
        unsigned a1 = __shfl((int)w[2*ks2][1],     srcA);
        unsigned b1 = __shfl((int)w[2*ks2 + 1][1], srcA);
        unsigned a2 = __shfl((int)w[2*ks2][0],     srcB);
        unsigned b2 = __shfl((int)w[2*ks2 + 1][0], srcB);
        unsigned a3 = __shfl((int)w[2*ks2][1],     srcB);
        unsigned b3 = __shfl((int)w[2*ks2 + 1][1], srcB);
        union { unsigned u[4]; bf16x8 v; } pk;
        pk.u[0] = hi ? b0 : a0;
        pk.u[1] = hi ? b1 : a1;
        pk.u[2] = hi ? b2 : a2;
        pk.u[3] = hi ? b3 : a3;
        pa[ks2] = pk.v;
      }
      #pragma unroll
      for (int ks2 = 0; ks2 < 2; ++ks2){
        int colsw = ((ks2 << 5) + lk) ^ sw8;
        #pragma unroll
        for (int db = 0; db < 8; ++db){
          bf16x8 vb = *reinterpret_cast<const bf16x8*>(&smem[kb + 8192 + ((db << 4) + l16) * 64 + colsw]);
          o[db] = mfma16(pa[ks2], vb, o[db]);
        }
      }
      __syncthreads();
      cur ^= 1;
    }
    #pragma unroll
    for (int j = 0; j < 4; ++j){
      float lv = __shfl(l, r4 + j);
      float rinv = 1.f / lv;
      const int tq = qlo + r4 + j;
      u16* dst = aout + (bT + tq) * 2048 + (h << 7) + l16;
      #pragma unroll
      for (int db = 0; db < 8; ++db)
        dst[db << 4] = f2bf(o[db][j] * rinv);
    }
  }
}

extern "C" void kernel_launch(void* const* d_in, const int* in_sizes, int n_in,
                              void* d_out, int out_size, void* d_ws, size_t ws_size,
                              hipStream_t stream){
  const void* x       = d_in[0];
  const void* cosp    = d_in[1];
  const void* sinp    = d_in[2];
  const void* w_kv    = d_in[3];
  const void* w_kdec  = d_in[4];
  const void* w_vdec  = d_in[5];
  const void* w_qc    = d_in[6];
  const void* w_qdec  = d_in[7];
  const void* w_krope = d_in[8];
  const void* w_qrope = d_in[9];
  const void* w_o     = d_in[10];

  char* ws = (char*)d_ws;
  size_t off = 0;
  auto alloc = [&](size_t bytes){ void* p = ws + off; off += (bytes + 255) & ~(size_t)255; return p; };
  int* flag     = (int*)alloc(256);
  int* ticket   = (int*)alloc(256);
  u16* x_bf     = (u16*)alloc((size_t)NROWS * DIM_ * 2);
  u16* w_c1T    = (u16*)alloc((size_t)2304 * DIM_ * 2);      // [kvT(512); qcT(1536); kropeT(64); qropeT(64); pad(128)] x 2048
  u16* w_kvdT   = (u16*)alloc((size_t)3072 * DC_ * 2);       // [kdecPackedT(1024); vdecT(2048)] x 512
  u16* w_qdPT   = (u16*)alloc((size_t)1024 * DCQ_ * 2);      // packed qdecT (1024 x 1536)
  u16* w_oT     = (u16*)alloc((size_t)DIM_ * DIM_ * 2);
  u16* xc       = (u16*)alloc((size_t)NROWS * 2304 * 2);     // [c_kv(512) | c_q(1536) | ropes(128) | pad(128)]
  u16* qP       = (u16*)alloc((size_t)NROWS * 1024 * 2);     // packed q decode (pre-scaled)
  u16* kvP      = (u16*)alloc((size_t)NROWS * 3072 * 2);     // [kPacked(1024) | v(2048)]
  u16* krope    = (u16*)alloc((size_t)NROWS * 64 * 2);
  u16* qrope    = (u16*)alloc((size_t)NROWS * 64 * 2);       // pre-scaled
  u16* vT       = (u16*)alloc((size_t)32 * 128 * T_ * 2);    // [bh][d][t]
  u16* aout     = (u16*)alloc((size_t)NROWS * DIM_ * 2);
  (void)in_sizes; (void)n_in; (void)out_size; (void)ws_size;

  const float SC2 = 0.12753139626374414f;   // 1/sqrt(128) * log2(e)

  hipLaunchKernelGGL(k_detect, dim3(1), dim3(64), 0, stream, (const u16*)cosp, flag, ticket);

  int n4 = NROWS * DIM_ / 4;
  hipLaunchKernelGGL(k_conv, dim3((n4 + 255) / 256), dim3(256), 0, stream, x, x_bf, n4, flag);

  // weight transposes into combined buffers (grid = (dstRows/64, srcRows/64))
  hipLaunchKernelGGL(k_transpose, dim3(8,  32), dim3(256), 0, stream, w_kv,    w_c1T,                        512,  2048, 64,  flag);
  hipLaunchKernelGGL(k_transpose, dim3(24, 32), dim3(256), 0, stream, w_qc,    w_c1T + (size_t)512 * 2048,   1536, 2048, 64,  flag);
  hipLaunchKernelGGL(k_transpose, dim3(1,  32), dim3(256), 0, stream, w_krope, w_c1T + (size_t)2048 * 2048,  64,   2048, 64,  flag);
  hipLaunchKernelGGL(k_transpose, dim3(1,  32), dim3(256), 0, stream, w_qrope, w_c1T + (size_t)2112 * 2048,  64,   2048, 64,  flag);
  hipLaunchKernelGGL(k_transpose, dim3(16, 8),  dim3(256), 0, stream, w_kdec,  w_kvdT,                       2048, 512,  128, flag);
  hipLaunchKernelGGL(k_transpose, dim3(32, 8),  dim3(256), 0, stream, w_vdec,  w_kvdT + (size_t)1024 * 512,  2048, 512,  64,  flag);
  hipLaunchKernelGGL(k_transpose, dim3(16, 24), dim3(256), 0, stream, w_qdec,  w_qdPT,                       2048, 1536, 128, flag);
  hipLaunchKernelGGL(k_transpose, dim3(32, 32), dim3(256), 0, stream, w_o,     w_oT,                         2048, 2048, 64,  flag);

  // G13: xc = x @ [w_kv | w_qc | w_krope | w_qrope | pad]  (4096 x 2304, K=2048)
  hipLaunchKernelGGL(k_gemm256, dim3(16, 9), dim3(512), 0, stream,
                     x_bf, DIM_, w_c1T, DIM_, xc, 2304, 1.0f,
                     x_bf, DIM_, w_c1T, DIM_, xc, 2304, 1.0f,
                     9, (void*)nullptr, (const int*)nullptr);
  // G2 + G4 grouped (256 blocks):
  //   y<12: kvP = xc[:, :512] @ [w_kdecP | w_vdec]   (4096 x 3072, K=512)
  //   y>=12: qP = xc[:, 512:2048] @ w_qdecP          (4096 x 1024, K=1536), pre-scaled
  hipLaunchKernelGGL(k_gemm256, dim3(16, 16), dim3(512), 0, stream,
                     xc, 2304, w_kvdT, DC_, kvP, 3072, 1.0f,
                     xc + 512, 2304, w_qdPT, DCQ_, qP, 1024, SC2,
                     12, (void*)nullptr, (const int*)nullptr);
  // RoPE (q-part pre-scaled)
  hipLaunchKernelGGL(k_rope, dim3(NROWS * 128 / 256), dim3(256), 0, stream,
                     xc + 2048, cosp, sinp, flag, krope, qrope);
  // vT[bh][d][t]
  hipLaunchKernelGGL(k_vt, dim3(T_/64, 2, 32), dim3(256), 0, stream, kvP, vT);
  // attention (persistent, 512 worker blocks = 2/CU, 1024 items)
  hipLaunchKernelGGL(k_attn, dim3(512), dim3(256), 0, stream,
                     qP, kvP, vT, krope, qrope, aout, ticket);
  // G5: out = aout @ w_o  (4096 x 2048, K=2048; writes d_out, dtype per flag)
  hipLaunchKernelGGL(k_gemm256, dim3(16, 8), dim3(512), 0, stream,
                     aout, DIM_, w_oT, DIM_, (u16*)nullptr, DIM_, 1.0f,
                     aout, DIM_, w_oT, DIM_, (u16*)nullptr, DIM_, 1.0f,
                     8, d_out, (const int*)flag);
}

// Round 8
// 314.616 us; speedup vs baseline: 1.5798x; 1.0428x over previous
//
#include <hip/hip_runtime.h>
#include <stdint.h>
#include <math.h>

#define B_    2
#define T_    2048
#define DIM_  2048
#define H_    16
#define DC_   512
#define DCQ_  1536
#define NROWS (B_*T_)   // 4096
#define NITEMS 1024

typedef unsigned short u16;
typedef __attribute__((ext_vector_type(8))) __bf16 bf16x8;
typedef __attribute__((ext_vector_type(4))) float  f32x4;
typedef __attribute__((ext_vector_type(8))) unsigned short u16x8;
typedef __attribute__((ext_vector_type(4))) float  f4v;

__device__ __forceinline__ u16 f2bf(float f){
  unsigned u = __float_as_uint(f);
  u += 0x7FFFu + ((u >> 16) & 1u);   // RNE
  return (u16)(u >> 16);
}
__device__ __forceinline__ float bf2f(u16 h){ return __uint_as_float(((unsigned)h) << 16); }

__device__ __forceinline__ unsigned cvt_pk_bf16(float lo, float hi){
  unsigned r;
  asm("v_cvt_pk_bf16_f32 %0, %1, %2" : "=v"(r) : "v"(lo), "v"(hi));
  return r;
}

// async global->LDS, 16B per lane; LDS dest = wave-uniform base + lane*16.
__device__ __forceinline__ void gld_lds16(const void* g, void* l){
  auto gp = reinterpret_cast<__attribute__((address_space(1))) unsigned int*>(
      reinterpret_cast<uintptr_t>(g));
  auto lp = reinterpret_cast<__attribute__((address_space(3))) unsigned int*>(
      reinterpret_cast<uintptr_t>(l));
  __builtin_amdgcn_global_load_lds(gp, lp, 16, 0, 0);
}

__device__ __forceinline__ f32x4 mfma16(bf16x8 a, bf16x8 b, f32x4 c){
  return __builtin_amdgcn_mfma_f32_16x16x32_bf16(a, b, c, 0, 0, 0);
}

__device__ __forceinline__ void vmwait0(){ asm volatile("s_waitcnt vmcnt(0)" ::: "memory"); }
__device__ __forceinline__ void barr(){ asm volatile("s_barrier" ::: "memory"); }

// ---------------- dtype detect + ticket reset
__global__ void k_detect(const u16* cosr, int* flag, int* ticket){
  if (threadIdx.x == 0){
    *flag = (cosr[0] == (u16)0x3F80u) ? 1 : 0;
    *ticket = 0;
  }
}

// ---------------- convert to bf16
__global__ void k_conv(const void* __restrict__ src, u16* __restrict__ dst, int n4, const int* flag){
  int id = blockIdx.x * 256 + threadIdx.x;
  if (id >= n4) return;
  if (*flag){
    reinterpret_cast<uint2*>(dst)[id] = reinterpret_cast<const uint2*>(src)[id];
  } else {
    f4v v = reinterpret_cast<const f4v*>(src)[id];
    unsigned lo = (unsigned)f2bf(v.x) | ((unsigned)f2bf(v.y) << 16);
    unsigned hi = (unsigned)f2bf(v.z) | ((unsigned)f2bf(v.w) << 16);
    reinterpret_cast<uint2*>(dst)[id] = make_uint2(lo, hi);
  }
}

// ---------------- transpose+convert to bf16 with optional column packing.
__global__ void k_transpose(const void* __restrict__ src, u16* __restrict__ dst,
                            int srcStride, int dstStride, int cblk, const int* flag){
  __shared__ u16 tile[64][72];
  const int r0 = blockIdx.y << 6, c0 = blockIdx.x * cblk;
  const int tid = threadIdx.x;
  const int f = *flag;
  #pragma unroll
  for (int i = 0; i < 2; ++i){
    int task = (i << 8) + tid;
    int r = task >> 3, c8 = (task & 7) << 3;
    if (f){
      const u16* p = (const u16*)src + (size_t)(r0 + r) * srcStride + c0 + c8;
      u16x8 v = *reinterpret_cast<const u16x8*>(p);
      #pragma unroll
      for (int j = 0; j < 8; ++j) tile[r][c8 + j] = v[j];
    } else {
      const float* p = (const float*)src + (size_t)(r0 + r) * srcStride + c0 + c8;
      f4v a = reinterpret_cast<const f4v*>(p)[0];
      f4v b = reinterpret_cast<const f4v*>(p)[1];
      tile[r][c8+0]=f2bf(a.x); tile[r][c8+1]=f2bf(a.y); tile[r][c8+2]=f2bf(a.z); tile[r][c8+3]=f2bf(a.w);
      tile[r][c8+4]=f2bf(b.x); tile[r][c8+5]=f2bf(b.y); tile[r][c8+6]=f2bf(b.z); tile[r][c8+7]=f2bf(b.w);
    }
  }
  __syncthreads();
  #pragma unroll
  for (int i = 0; i < 2; ++i){
    int task = (i << 8) + tid;
    int rr = task >> 3, cc8 = (task & 7) << 3;
    u16x8 v;
    #pragma unroll
    for (int j = 0; j < 8; ++j) v[j] = tile[cc8 + j][rr];
    *reinterpret_cast<u16x8*>(dst + (size_t)((blockIdx.x << 6) + rr) * dstStride + r0 + cc8) = v;
  }
}

// ---------------- build vT[bh][d][t] from kvP cols 1024 + h*128 + d
__global__ void k_vt(const u16* __restrict__ kvP, u16* __restrict__ vT){
  __shared__ u16 tile[64][72];
  const int t0 = blockIdx.x << 6, d0 = blockIdx.y << 6, bh = blockIdx.z;
  const int b = bh >> 4, h = bh & 15;
  const int tid = threadIdx.x;
  #pragma unroll
  for (int i = 0; i < 2; ++i){
    int task = (i << 8) + tid;
    int r = task >> 3, c8 = (task & 7) << 3;
    const u16* p = kvP + (size_t)(b * T_ + t0 + r) * 3072 + 1024 + h * 128 + d0 + c8;
    u16x8 v = *reinterpret_cast<const u16x8*>(p);
    #pragma unroll
    for (int j = 0; j < 8; ++j) tile[r][c8 + j] = v[j];
  }
  __syncthreads();
  #pragma unroll
  for (int i = 0; i < 2; ++i){
    int task = (i << 8) + tid;
    int rr = task >> 3, cc8 = (task & 7) << 3;
    u16x8 v;
    #pragma unroll
    for (int j = 0; j < 8; ++j) v[j] = tile[cc8 + j][rr];
    *reinterpret_cast<u16x8*>(vT + ((size_t)bh * 128 + d0 + rr) * T_ + t0 + cc8) = v;
  }
}

// ---------------- 256x256 8-phase GEMM (2 groups selectable by blockIdx.y).
// C(MxN) = A(MxK, lda) * Bt(NxK row-major), bf16 in, fp32 acc. M%256==0, N%256==0, K%64==0.
// 512 thr = 8 waves (2M x 4N), 128x64 per wave. LDS 128KB: 2 buffers x 4 half-tiles [128][64],
// row-XOR swizzle: 16B slot ^= (row&7)  (byte ^= ((row&7)<<4)) -- 8-slot spread, 2 lanes/slot
// on the 16-row fragment reads (G4 form; the old st_16x32 formula was an 8-way conflict).
// Applied via inverse-swizzled global_load_lds sources (involution), linear LDS dest.
// Per K-tile: stage kt+1 at phase0; 4 phases {ds_read, barrier, setprio+16 MFMA, barrier};
// vmcnt(0) only at tile boundary (loads issued 4 phases earlier -> latency covered).
#define MMQ(MH, NH, BFR) do{ \
  __builtin_amdgcn_s_setprio(1); \
  _Pragma("unroll") for (int ks = 0; ks < 2; ++ks) \
    _Pragma("unroll") for (int mi = 0; mi < 4; ++mi) \
      _Pragma("unroll") for (int ni = 0; ni < 2; ++ni) \
        acc[(MH)*4+mi][(NH)*2+ni] = mfma16(af[ks][mi], BFR[ks][ni], acc[(MH)*4+mi][(NH)*2+ni]); \
  __builtin_amdgcn_s_setprio(0); \
}while(0)

#define LDA(MH) do{ \
  _Pragma("unroll") for (int ks = 0; ks < 2; ++ks) \
    _Pragma("unroll") for (int mi = 0; mi < 4; ++mi){ \
      int row = (MH)*64 + mi*16 + l16; \
      int cb = ((ks << 6) + (g << 4)) ^ ((row & 7) << 4); \
      af[ks][mi] = *reinterpret_cast<const bf16x8*>(&lds[buf*32768 + wm*8192 + (((row << 7) + cb) >> 1)]); \
    } \
}while(0)

#define LDB(DST, NH) do{ \
  _Pragma("unroll") for (int ks = 0; ks < 2; ++ks) \
    _Pragma("unroll") for (int ni = 0; ni < 2; ++ni){ \
      int row = ((wn & 1) * 64) + (NH)*32 + ni*16 + l16; \
      int cb = ((ks << 6) + (g << 4)) ^ ((row & 7) << 4); \
      DST[ks][ni] = *reinterpret_cast<const bf16x8*>(&lds[buf*32768 + 16384 + (wn >> 1)*8192 + (((row << 7) + cb) >> 1)]); \
    } \
}while(0)

__global__ __launch_bounds__(512, 2) void k_gemm256(
    const u16* __restrict__ A0, int lda0, const u16* __restrict__ Bt0, int K0,
    u16* __restrict__ C0, int ldc0, float os0,
    const u16* __restrict__ A1, int lda1, const u16* __restrict__ Bt1, int K1,
    u16* __restrict__ C1, int ldc1, float os1,
    int ysplit, void* outp, const int* flag){
  __shared__ alignas(16) u16 lds[65536];   // 128 KB
  const int tid = threadIdx.x;
  const int wid = tid >> 6, lane = tid & 63;
  const int wm = wid >> 2, wn = wid & 3;
  const int l16 = lane & 15, g = lane >> 4;
  int by = blockIdx.y;
  const u16 *A, *Bt; u16* C; int lda, K, ldc; float oscale;
  if (by < ysplit){ A = A0; lda = lda0; Bt = Bt0; K = K0; C = C0; ldc = ldc0; oscale = os0; }
  else { by -= ysplit; A = A1; lda = lda1; Bt = Bt1; K = K1; C = C1; ldc = ldc1; oscale = os1; }
  const int m0 = blockIdx.x << 8, n0 = by << 8;
  const size_t Kz = (size_t)K;
  const int nkt = K >> 6;

  auto STAGE = [&](int kt, int bufn){
    const int kb = kt << 6;
    #pragma unroll
    for (int q = 0; q < 8; ++q){
      const int ht = q >> 1, ch = q & 1;
      const int Lb = ((ch * 8 + wid) << 10) + (lane << 4);   // byte within half-tile
      const int row = Lb >> 7;
      const int colb = (Lb & 127) ^ ((row & 7) << 4);        // inverse-swizzled source
      const u16* src;
      if (ht < 2) src = A  + (size_t)(m0 + ht * 128 + row) * lda + kb + (colb >> 1);
      else        src = Bt + (size_t)(n0 + (ht - 2) * 128 + row) * Kz + kb + (colb >> 1);
      gld_lds16(src, &lds[bufn * 32768 + ht * 8192 + ((ch * 8 + wid) << 9)]);
    }
  };

  f32x4 acc[8][4] = {};
  bf16x8 af[2][4], bf0[2][2], bf1[2][2];

  STAGE(0, 0);
  vmwait0();
  barr();
  int buf = 0;

  for (int kt = 0; kt < nkt; ++kt){
    // phase 0: stage kt+1, read A[mh0] + B[nh0], compute (mh0,nh0)
    if (kt + 1 < nkt) STAGE(kt + 1, buf ^ 1);
    LDA(0);
    LDB(bf0, 0);
    barr();
    MMQ(0, 0, bf0);
    barr();
    // phase 1: read B[nh1], compute (mh0,nh1)
    LDB(bf1, 1);
    barr();
    MMQ(0, 1, bf1);
    barr();
    // phase 2: read A[mh1], compute (mh1,nh0)
    LDA(1);
    barr();
    MMQ(1, 0, bf0);
    barr();
    // phase 3: compute (mh1,nh1), then drain prefetch
    barr();
    MMQ(1, 1, bf1);
    vmwait0();
    barr();
    buf ^= 1;
  }

  const int r4 = g << 2;
  const int f = flag ? *flag : 1;
  #pragma unroll
  for (int mi8 = 0; mi8 < 8; ++mi8){
    int row = m0 + wm * 128 + mi8 * 16 + r4;
    #pragma unroll
    for (int ni4 = 0; ni4 < 4; ++ni4){
      int col = n0 + wn * 64 + ni4 * 16 + l16;
      #pragma unroll
      for (int j = 0; j < 4; ++j){
        float v = acc[mi8][ni4][j] * oscale;
        if (outp){
          if (f) ((u16*)outp)[(size_t)(row + j) * ldc + col] = f2bf(v);
          else   ((float*)outp)[(size_t)(row + j) * ldc + col] = v;
        } else {
          C[(size_t)(row + j) * ldc + col] = f2bf(v);
        }
      }
    }
  }
}

// ---------------- RoPE from xc cols 2048..2175 (stride 2304); q-part pre-scaled by 1/sqrt(D)*log2e
__global__ void k_rope(const u16* __restrict__ ropes, const void* __restrict__ cosp,
                       const void* __restrict__ sinp, const int* flag,
                       u16* __restrict__ krope, u16* __restrict__ qrope){
  int id = blockIdx.x * 256 + threadIdx.x;
  if (id >= NROWS * 128) return;
  int row = id >> 7, c = id & 127;
  int t = row & (T_ - 1);
  int d = c & 63, i = d & 31;
  float cs, sn;
  if (*flag){ cs = bf2f(((const u16*)cosp)[t * 32 + i]); sn = bf2f(((const u16*)sinp)[t * 32 + i]); }
  else      { cs = ((const float*)cosp)[t * 32 + i];     sn = ((const float*)sinp)[t * 32 + i]; }
  int base = c & 64;
  float t1 = bf2f(ropes[(size_t)row * 2304 + base + i]);
  float t2 = bf2f(ropes[(size_t)row * 2304 + base + 32 + i]);
  float v = (d < 32) ? (t1 * cs - t2 * sn) : (t2 * cs + t1 * sn);
  if (c >= 64) v *= 0.12753139626374414f;   // 1/sqrt(128) * log2(e), folded into q
  ((c < 64) ? krope : qrope)[(size_t)row * 64 + d] = f2bf(v);
}

// ---------------- causal flash attention, swapped-QK^T register softmax (round-6, unchanged).
__global__ __launch_bounds__(256, 2) void k_attn(const u16* __restrict__ qP,
                                                 const u16* __restrict__ kvP,
                                                 const u16* __restrict__ vT,
                                                 const u16* __restrict__ krope,
                                                 const u16* __restrict__ qrope,
                                                 u16* __restrict__ aout,
                                                 int* __restrict__ ticket){
  __shared__ alignas(16) u16 smem[32768];   // 64 KB -> 2 blocks/CU
  const int tid = threadIdx.x, wid = tid >> 6, lane = tid & 63;
  const int l16 = lane & 15, g = lane >> 4;
  const int lk = g << 3, r4 = g << 2;
  const int sw8 = (l16 & 7) << 3;

  while (true){
    if (tid == 0) *(int*)&smem[0] = atomicAdd(ticket, 1);
    __syncthreads();
    const int it = *(const int*)&smem[0];
    __syncthreads();
    if (it >= NITEMS) break;
    const int qt = 31 - (it >> 5);          // heavy-first
    const int bh = it & 31, b = bh >> 4, h = bh & 15;
    const int q0 = qt << 6;
    const size_t bT = (size_t)b * T_;
    const u16* kvPb = kvP + bT * 3072 + (h << 6);
    const u16* krb  = krope + bT * 64;
    const u16* vTb  = vT + (size_t)bh * 128 * T_;
    const int qlo = q0 + (wid << 4);
    const int nkv = qt + 1;

    auto STAGE = [&](int buf, int k0){
      const int base = buf << 14;
      #pragma unroll
      for (int r = 0; r < 8; ++r){
        int c = (r << 8) + tid;
        const u16* src;
        if (r < 4){
          int row = c >> 4, cc = c & 15;
          int ccx = (cc & 8) | ((cc & 7) ^ (row & 7));
          int col0 = ccx << 3;
          src = (col0 < 64) ? (kvPb + (size_t)(k0 + row) * 3072 + col0)
                            : (krb  + (size_t)(k0 + row) * 64 + (col0 - 64));
        } else {
          int cv = c - 1024;
          int row = cv >> 3, cc = cv & 7;
          int ccx = cc ^ (row & 7);
          src = vTb + (size_t)row * T_ + k0 + (ccx << 3);
        }
        gld_lds16(src, &smem[base + (((r << 8) + (wid << 6)) << 3)]);
      }
    };

    bf16x8 qf[4];
    {
      size_t grow = bT + qlo + l16;
      #pragma unroll
      for (int ks = 0; ks < 4; ++ks){
        int d = (ks << 5) + lk;
        const u16* src = (ks < 2) ? (qP + grow * 1024 + (h << 6) + d)
                                  : (qrope + grow * 64 + (d - 64));
        qf[ks] = *reinterpret_cast<const bf16x8*>(src);
      }
    }
    f32x4 o[8] = {};
    float m = -3e38f, l = 0.f;

    STAGE(0, 0);
    __syncthreads();
    int cur = 0;

    for (int kv = 0; kv < nkv; ++kv){
      const int k0 = kv << 6;
      if (kv + 1 < nkv) STAGE(cur ^ 1, (kv + 1) << 6);
      const int kb = cur << 14;
      f32x4 s[4] = {};
      #pragma unroll
      for (int ks = 0; ks < 4; ++ks){
        int colsw = ((ks << 5) + lk) ^ sw8;
        #pragma unroll
        for (int n = 0; n < 4; ++n){
          bf16x8 kf = *reinterpret_cast<const bf16x8*>(&smem[kb + ((n << 4) + l16) * 128 + colsw]);
          s[n] = mfma16(kf, qf[ks], s[n]);
        }
      }
      if (k0 == q0){
        const int tq = qlo + l16;
        #pragma unroll
        for (int n = 0; n < 4; ++n)
          #pragma unroll
          for (int j = 0; j < 4; ++j)
            s[n][j] = (k0 + (n << 4) + r4 + j <= tq) ? s[n][j] : -3e38f;
      }
      float mx;
      {
        float a0 = fmaxf(fmaxf(s[0][0], s[0][1]), fmaxf(s[0][2], s[0][3]));
        float a1 = fmaxf(fmaxf(s[1][0], s[1][1]), fmaxf(s[1][2], s[1][3]));
        float a2 = fmaxf(fmaxf(s[2][0], s[2][1]), fmaxf(s[2][2], s[2][3]));
        float a3 = fmaxf(fmaxf(s[3][0], s[3][1]), fmaxf(s[3][2], s[3][3]));
        mx = fmaxf(fmaxf(a0, a1), fmaxf(a2, a3));
        mx = fmaxf(mx, __shfl_xor(mx, 16));
        mx = fmaxf(mx, __shfl_xor(mx, 32));
      }
      if (__ballot(mx > m + 8.f)){
        float mnew = fmaxf(m, mx);
        float alpha = exp2f(m - mnew);
        m = mnew; l *= alpha;
        #pragma unroll
        for (int j = 0; j < 4; ++j){
          float av = __shfl(alpha, r4 + j);
          #pragma unroll
          for (int db = 0; db < 8; ++db) o[db][j] *= av;
        }
      }
      unsigned w[4][2];
      float rs = 0.f;
      #pragma unroll
      for (int n = 0; n < 4; ++n)
        #pragma unroll
        for (int jh = 0; jh < 2; ++jh){
          float p0 = exp2f(s[n][2*jh]     - m);
          float p1 = exp2f(s[n][2*jh + 1] - m);
          rs += p0 + p1;
          w[n][jh] = cvt_pk_bf16(p0, p1);
        }
      rs += __shfl_xor(rs, 16);
      rs += __shfl_xor(rs, 32);
      l += rs;
      const int srcA = l16 + ((g & 1) << 5);
      const int srcB = srcA + 16;
      const bool hi = (g >= 2);
      bf16x8 pa[2];
      #pragma unroll
      for (int ks2 = 0; ks2 < 2; ++ks2){
        unsigned a0 = __shfl((int)w[2*ks2][0],     srcA);
        unsigned b0 = __shfl((int)w[2*ks2 + 1][0], srcA);
        unsigned a1 = __shfl((int)w[2*ks2][1],     srcA);
        unsigned b1 = __shfl((int)w[2*ks2 + 1][1], srcA);
        unsigned a2 = __shfl((int)w[2*ks2][0],     srcB);
        unsigned b2 = __shfl((int)w[2*ks2 + 1][0], srcB);
        unsigned a3 = __shfl((int)w[2*ks2][1],     srcB);
        unsigned b3 = __shfl((int)w[2*ks2 + 1][1], srcB);
        union { unsigned u[4]; bf16x8 v; } pk;
        pk.u[0] = hi ? b0 : a0;
        pk.u[1] = hi ? b1 : a1;
        pk.u[2] = hi ? b2 : a2;
        pk.u[3] = hi ? b3 : a3;
        pa[ks2] = pk.v;
      }
      #pragma unroll
      for (int ks2 = 0; ks2 < 2; ++ks2){
        int colsw = ((ks2 << 5) + lk) ^ sw8;
        #pragma unroll
        for (int db = 0; db < 8; ++db){
          bf16x8 vb = *reinterpret_cast<const bf16x8*>(&smem[kb + 8192 + ((db << 4) + l16) * 64 + colsw]);
          o[db] = mfma16(pa[ks2], vb, o[db]);
        }
      }
      __syncthreads();
      cur ^= 1;
    }
    #pragma unroll
    for (int j = 0; j < 4; ++j){
      float lv = __shfl(l, r4 + j);
      float rinv = 1.f / lv;
      const int tq = qlo + r4 + j;
      u16* dst = aout + (bT + tq) * 2048 + (h << 7) + l16;
      #pragma unroll
      for (int db = 0; db < 8; ++db)
        dst[db << 4] = f2bf(o[db][j] * rinv);
    }
  }
}

extern "C" void kernel_launch(void* const* d_in, const int* in_sizes, int n_in,
                              void* d_out, int out_size, void* d_ws, size_t ws_size,
                              hipStream_t stream){
  const void* x       = d_in[0];
  const void* cosp    = d_in[1];
  const void* sinp    = d_in[2];
  const void* w_kv    = d_in[3];
  const void* w_kdec  = d_in[4];
  const void* w_vdec  = d_in[5];
  const void* w_qc    = d_in[6];
  const void* w_qdec  = d_in[7];
  const void* w_krope = d_in[8];
  const void* w_qrope = d_in[9];
  const void* w_o     = d_in[10];

  char* ws = (char*)d_ws;
  size_t off = 0;
  auto alloc = [&](size_t bytes){ void* p = ws + off; off += (bytes + 255) & ~(size_t)255; return p; };
  int* flag     = (int*)alloc(256);
  int* ticket   = (int*)alloc(256);
  u16* x_bf     = (u16*)alloc((size_t)NROWS * DIM_ * 2);
  u16* w_c1T    = (u16*)alloc((size_t)2304 * DIM_ * 2);      // [kvT(512); qcT(1536); kropeT(64); qropeT(64); pad(128)] x 2048
  u16* w_kvdT   = (u16*)alloc((size_t)3072 * DC_ * 2);       // [kdecPackedT(1024); vdecT(2048)] x 512
  u16* w_qdPT   = (u16*)alloc((size_t)1024 * DCQ_ * 2);      // packed qdecT (1024 x 1536)
  u16* w_oT     = (u16*)alloc((size_t)DIM_ * DIM_ * 2);
  u16* xc       = (u16*)alloc((size_t)NROWS * 2304 * 2);     // [c_kv(512) | c_q(1536) | ropes(128) | pad(128)]
  u16* qP       = (u16*)alloc((size_t)NROWS * 1024 * 2);     // packed q decode (pre-scaled)
  u16* kvP      = (u16*)alloc((size_t)NROWS * 3072 * 2);     // [kPacked(1024) | v(2048)]
  u16* krope    = (u16*)alloc((size_t)NROWS * 64 * 2);
  u16* qrope    = (u16*)alloc((size_t)NROWS * 64 * 2);       // pre-scaled
  u16* vT       = (u16*)alloc((size_t)32 * 128 * T_ * 2);    // [bh][d][t]
  u16* aout     = (u16*)alloc((size_t)NROWS * DIM_ * 2);
  (void)in_sizes; (void)n_in; (void)out_size; (void)ws_size;

  const float SC2 = 0.12753139626374414f;   // 1/sqrt(128) * log2(e)

  hipLaunchKernelGGL(k_detect, dim3(1), dim3(64), 0, stream, (const u16*)cosp, flag, ticket);

  int n4 = NROWS * DIM_ / 4;
  hipLaunchKernelGGL(k_conv, dim3((n4 + 255) / 256), dim3(256), 0, stream, x, x_bf, n4, flag);

  // weight transposes into combined buffers (grid = (dstRows/64, srcRows/64))
  hipLaunchKernelGGL(k_transpose, dim3(8,  32), dim3(256), 0, stream, w_kv,    w_c1T,                        512,  2048, 64,  flag);
  hipLaunchKernelGGL(k_transpose, dim3(24, 32), dim3(256), 0, stream, w_qc,    w_c1T + (size_t)512 * 2048,   1536, 2048, 64,  flag);
  hipLaunchKernelGGL(k_transpose, dim3(1,  32), dim3(256), 0, stream, w_krope, w_c1T + (size_t)2048 * 2048,  64,   2048, 64,  flag);
  hipLaunchKernelGGL(k_transpose, dim3(1,  32), dim3(256), 0, stream, w_qrope, w_c1T + (size_t)2112 * 2048,  64,   2048, 64,  flag);
  hipLaunchKernelGGL(k_transpose, dim3(16, 8),  dim3(256), 0, stream, w_kdec,  w_kvdT,                       2048, 512,  128, flag);
  hipLaunchKernelGGL(k_transpose, dim3(32, 8),  dim3(256), 0, stream, w_vdec,  w_kvdT + (size_t)1024 * 512,  2048, 512,  64,  flag);
  hipLaunchKernelGGL(k_transpose, dim3(16, 24), dim3(256), 0, stream, w_qdec,  w_qdPT,                       2048, 1536, 128, flag);
  hipLaunchKernelGGL(k_transpose, dim3(32, 32), dim3(256), 0, stream, w_o,     w_oT,                         2048, 2048, 64,  flag);

  // G13: xc = x @ [w_kv | w_qc | w_krope | w_qrope | pad]  (4096 x 2304, K=2048)
  hipLaunchKernelGGL(k_gemm256, dim3(16, 9), dim3(512), 0, stream,
                     x_bf, DIM_, w_c1T, DIM_, xc, 2304, 1.0f,
                     x_bf, DIM_, w_c1T, DIM_, xc, 2304, 1.0f,
                     9, (void*)nullptr, (const int*)nullptr);
  // G2 + G4 grouped (256 blocks):
  //   y<12: kvP = xc[:, :512] @ [w_kdecP | w_vdec]   (4096 x 3072, K=512)
  //   y>=12: qP = xc[:, 512:2048] @ w_qdecP          (4096 x 1024, K=1536), pre-scaled
  hipLaunchKernelGGL(k_gemm256, dim3(16, 16), dim3(512), 0, stream,
                     xc, 2304, w_kvdT, DC_, kvP, 3072, 1.0f,
                     xc + 512, 2304, w_qdPT, DCQ_, qP, 1024, SC2,
                     12, (void*)nullptr, (const int*)nullptr);
  // RoPE (q-part pre-scaled)
  hipLaunchKernelGGL(k_rope, dim3(NROWS * 128 / 256), dim3(256), 0, stream,
                     xc + 2048, cosp, sinp, flag, krope, qrope);
  // vT[bh][d][t]
  hipLaunchKernelGGL(k_vt, dim3(T_/64, 2, 32), dim3(256), 0, stream, kvP, vT);
  // attention (persistent, 512 worker blocks = 2/CU, 1024 items)
  hipLaunchKernelGGL(k_attn, dim3(512), dim3(256), 0, stream,
                     qP, kvP, vT, krope, qrope, aout, ticket);
  // G5: out = aout @ w_o  (4096 x 2048, K=2048; writes d_out, dtype per flag)
  hipLaunchKernelGGL(k_gemm256, dim3(16, 8), dim3(512), 0, stream,
                     aout, DIM_, w_oT, DIM_, (u16*)nullptr, DIM_, 1.0f,
                     aout, DIM_, w_oT, DIM_, (u16*)nullptr, DIM_, 1.0f,
                     8, d_out, (const int*)flag);
}

// Round 9
// 297.706 us; speedup vs baseline: 1.6696x; 1.0568x over previous
//
#include <hip/hip_runtime.h>
#include <stdint.h>
#include <math.h>

#define B_    2
#define T_    2048
#define DIM_  2048
#define H_    16
#define DC_   512
#define DCQ_  1536
#define NROWS (B_*T_)   // 4096

typedef unsigned short u16;
typedef __attribute__((ext_vector_type(8))) __bf16 bf16x8;
typedef __attribute__((ext_vector_type(4))) float  f32x4;
typedef __attribute__((ext_vector_type(8))) unsigned short u16x8;
typedef __attribute__((ext_vector_type(4))) float  f4v;

__device__ __forceinline__ u16 f2bf(float f){
  unsigned u = __float_as_uint(f);
  u += 0x7FFFu + ((u >> 16) & 1u);   // RNE
  return (u16)(u >> 16);
}
__device__ __forceinline__ float bf2f(u16 h){ return __uint_as_float(((unsigned)h) << 16); }

__device__ __forceinline__ unsigned cvt_pk_bf16(float lo, float hi){
  unsigned r;
  asm("v_cvt_pk_bf16_f32 %0, %1, %2" : "=v"(r) : "v"(lo), "v"(hi));
  return r;
}

// async global->LDS, 16B per lane; LDS dest = wave-uniform base + lane*16.
__device__ __forceinline__ void gld_lds16(const void* g, void* l){
  auto gp = reinterpret_cast<__attribute__((address_space(1))) unsigned int*>(
      reinterpret_cast<uintptr_t>(g));
  auto lp = reinterpret_cast<__attribute__((address_space(3))) unsigned int*>(
      reinterpret_cast<uintptr_t>(l));
  __builtin_amdgcn_global_load_lds(gp, lp, 16, 0, 0);
}

__device__ __forceinline__ f32x4 mfma16(bf16x8 a, bf16x8 b, f32x4 c){
  return __builtin_amdgcn_mfma_f32_16x16x32_bf16(a, b, c, 0, 0, 0);
}

__device__ __forceinline__ void vmwait0(){ asm volatile("s_waitcnt vmcnt(0)" ::: "memory"); }
__device__ __forceinline__ void vmwait8(){ asm volatile("s_waitcnt vmcnt(8)" ::: "memory"); }
__device__ __forceinline__ void barr(){ asm volatile("s_barrier" ::: "memory"); }

// ---------------- dtype detect + ticket reset (8 XCD-partition tickets, stride 16)
__global__ void k_detect(const u16* cosr, int* flag, int* ticket){
  if (threadIdx.x == 0) *flag = (cosr[0] == (u16)0x3F80u) ? 1 : 0;
  if (threadIdx.x < 128) ticket[threadIdx.x] = 0;
}

// ---------------- convert to bf16
__global__ void k_conv(const void* __restrict__ src, u16* __restrict__ dst, int n4, const int* flag){
  int id = blockIdx.x * 256 + threadIdx.x;
  if (id >= n4) return;
  if (*flag){
    reinterpret_cast<uint2*>(dst)[id] = reinterpret_cast<const uint2*>(src)[id];
  } else {
    f4v v = reinterpret_cast<const f4v*>(src)[id];
    unsigned lo = (unsigned)f2bf(v.x) | ((unsigned)f2bf(v.y) << 16);
    unsigned hi = (unsigned)f2bf(v.z) | ((unsigned)f2bf(v.w) << 16);
    reinterpret_cast<uint2*>(dst)[id] = make_uint2(lo, hi);
  }
}

// ---------------- merged transpose+convert (8 jobs, one launch)
struct TDesc { const void* src; u16* dst; int srcStride, dstStride, cblk, nbx, blk0; };
struct TPack { TDesc d[8]; };

__global__ void k_transpose8(TPack p, const int* flag){
  __shared__ u16 tile[64][72];
  const int bid = blockIdx.x;
  int i = 0;
  #pragma unroll
  for (int k = 1; k < 8; ++k) if (bid >= p.d[k].blk0) i = k;
  const void* src = p.d[i].src;
  u16* dst = p.d[i].dst;
  const int srcStride = p.d[i].srcStride, dstStride = p.d[i].dstStride;
  const int rel = bid - p.d[i].blk0;
  const int bx = rel % p.d[i].nbx, by = rel / p.d[i].nbx;
  const int r0 = by << 6, c0 = bx * p.d[i].cblk;
  const int tid = threadIdx.x;
  const int f = *flag;
  #pragma unroll
  for (int it = 0; it < 2; ++it){
    int task = (it << 8) + tid;
    int r = task >> 3, c8 = (task & 7) << 3;
    if (f){
      const u16* pp = (const u16*)src + (size_t)(r0 + r) * srcStride + c0 + c8;
      u16x8 v = *reinterpret_cast<const u16x8*>(pp);
      #pragma unroll
      for (int j = 0; j < 8; ++j) tile[r][c8 + j] = v[j];
    } else {
      const float* pp = (const float*)src + (size_t)(r0 + r) * srcStride + c0 + c8;
      f4v a = reinterpret_cast<const f4v*>(pp)[0];
      f4v b = reinterpret_cast<const f4v*>(pp)[1];
      tile[r][c8+0]=f2bf(a.x); tile[r][c8+1]=f2bf(a.y); tile[r][c8+2]=f2bf(a.z); tile[r][c8+3]=f2bf(a.w);
      tile[r][c8+4]=f2bf(b.x); tile[r][c8+5]=f2bf(b.y); tile[r][c8+6]=f2bf(b.z); tile[r][c8+7]=f2bf(b.w);
    }
  }
  __syncthreads();
  #pragma unroll
  for (int it = 0; it < 2; ++it){
    int task = (it << 8) + tid;
    int rr = task >> 3, cc8 = (task & 7) << 3;
    u16x8 v;
    #pragma unroll
    for (int j = 0; j < 8; ++j) v[j] = tile[cc8 + j][rr];
    *reinterpret_cast<u16x8*>(dst + (size_t)((bx << 6) + rr) * dstStride + r0 + cc8) = v;
  }
}

// ---------------- build vT[bh][d][t] from kvP cols 1024 + h*128 + d
__global__ void k_vt(const u16* __restrict__ kvP, u16* __restrict__ vT){
  __shared__ u16 tile[64][72];
  const int t0 = blockIdx.x << 6, d0 = blockIdx.y << 6, bh = blockIdx.z;
  const int b = bh >> 4, h = bh & 15;
  const int tid = threadIdx.x;
  #pragma unroll
  for (int i = 0; i < 2; ++i){
    int task = (i << 8) + tid;
    int r = task >> 3, c8 = (task & 7) << 3;
    const u16* p = kvP + (size_t)(b * T_ + t0 + r) * 3072 + 1024 + h * 128 + d0 + c8;
    u16x8 v = *reinterpret_cast<const u16x8*>(p);
    #pragma unroll
    for (int j = 0; j < 8; ++j) tile[r][c8 + j] = v[j];
  }
  __syncthreads();
  #pragma unroll
  for (int i = 0; i < 2; ++i){
    int task = (i << 8) + tid;
    int rr = task >> 3, cc8 = (task & 7) << 3;
    u16x8 v;
    #pragma unroll
    for (int j = 0; j < 8; ++j) v[j] = tile[cc8 + j][rr];
    *reinterpret_cast<u16x8*>(vT + ((size_t)bh * 128 + d0 + rr) * T_ + t0 + cc8) = v;
  }
}

// ---------------- 256x256 8-phase GEMM, counted-vmcnt pipeline (2 groups by blockIdx.y).
// Per K-tile: {STAGE(kt+1); vmcnt(8) -> waits tile-kt loads issued a FULL TILE ago; barrier;
// 4 phases of {ds_read quadrant, barrier, setprio+16 MFMA, barrier}}. Never vmcnt(0) mid-loop.
// Row-XOR swizzle byte ^= ((row&7)<<4) via inverse-swizzled global sources.
#define MMQ(MH, NH, BFR) do{ \
  __builtin_amdgcn_s_setprio(1); \
  _Pragma("unroll") for (int ks = 0; ks < 2; ++ks) \
    _Pragma("unroll") for (int mi = 0; mi < 4; ++mi) \
      _Pragma("unroll") for (int ni = 0; ni < 2; ++ni) \
        acc[(MH)*4+mi][(NH)*2+ni] = mfma16(af[ks][mi], BFR[ks][ni], acc[(MH)*4+mi][(NH)*2+ni]); \
  __builtin_amdgcn_s_setprio(0); \
}while(0)

#define LDA(MH) do{ \
  _Pragma("unroll") for (int ks = 0; ks < 2; ++ks) \
    _Pragma("unroll") for (int mi = 0; mi < 4; ++mi){ \
      int row = (MH)*64 + mi*16 + l16; \
      int cb = ((ks << 6) + (g << 4)) ^ ((row & 7) << 4); \
      af[ks][mi] = *reinterpret_cast<const bf16x8*>(&lds[buf*32768 + wm*8192 + (((row << 7) + cb) >> 1)]); \
    } \
}while(0)

#define LDB(DST, NH) do{ \
  _Pragma("unroll") for (int ks = 0; ks < 2; ++ks) \
    _Pragma("unroll") for (int ni = 0; ni < 2; ++ni){ \
      int row = ((wn & 1) * 64) + (NH)*32 + ni*16 + l16; \
      int cb = ((ks << 6) + (g << 4)) ^ ((row & 7) << 4); \
      DST[ks][ni] = *reinterpret_cast<const bf16x8*>(&lds[buf*32768 + 16384 + (wn >> 1)*8192 + (((row << 7) + cb) >> 1)]); \
    } \
}while(0)

__global__ __launch_bounds__(512, 2) void k_gemm256(
    const u16* __restrict__ A0, int lda0, const u16* __restrict__ Bt0, int K0,
    u16* __restrict__ C0, int ldc0, float os0,
    const u16* __restrict__ A1, int lda1, const u16* __restrict__ Bt1, int K1,
    u16* __restrict__ C1, int ldc1, float os1,
    int ysplit, void* outp, const int* flag){
  __shared__ alignas(16) u16 lds[65536];   // 128 KB
  const int tid = threadIdx.x;
  const int wid = tid >> 6, lane = tid & 63;
  const int wm = wid >> 2, wn = wid & 3;
  const int l16 = lane & 15, g = lane >> 4;
  int by = blockIdx.y;
  const u16 *A, *Bt; u16* C; int lda, K, ldc; float oscale;
  if (by < ysplit){ A = A0; lda = lda0; Bt = Bt0; K = K0; C = C0; ldc = ldc0; oscale = os0; }
  else { by -= ysplit; A = A1; lda = lda1; Bt = Bt1; K = K1; C = C1; ldc = ldc1; oscale = os1; }
  const int m0 = blockIdx.x << 8, n0 = by << 8;
  const size_t Kz = (size_t)K;
  const int nkt = K >> 6;

  auto STAGE = [&](int kt, int bufn){
    const int kb = kt << 6;
    #pragma unroll
    for (int q = 0; q < 8; ++q){
      const int ht = q >> 1, ch = q & 1;
      const int Lb = ((ch * 8 + wid) << 10) + (lane << 4);   // byte within half-tile
      const int row = Lb >> 7;
      const int colb = (Lb & 127) ^ ((row & 7) << 4);        // inverse-swizzled source
      const u16* src;
      if (ht < 2) src = A  + (size_t)(m0 + ht * 128 + row) * lda + kb + (colb >> 1);
      else        src = Bt + (size_t)(n0 + (ht - 2) * 128 + row) * Kz + kb + (colb >> 1);
      gld_lds16(src, &lds[bufn * 32768 + ht * 8192 + ((ch * 8 + wid) << 9)]);
    }
  };

  f32x4 acc[8][4] = {};
  bf16x8 af[2][4], bf0[2][2], bf1[2][2];

  STAGE(0, 0);
  int buf = 0;

  for (int kt = 0; kt < nkt; ++kt){
    if (kt + 1 < nkt){ STAGE(kt + 1, buf ^ 1); vmwait8(); }   // wait only tile-kt's loads
    else vmwait0();
    barr();                                                    // buf resident for all waves
    // phase 0
    LDA(0);
    LDB(bf0, 0);
    barr();
    MMQ(0, 0, bf0);
    barr();
    // phase 1
    LDB(bf1, 1);
    barr();
    MMQ(0, 1, bf1);
    barr();
    // phase 2
    LDA(1);
    barr();
    MMQ(1, 0, bf0);
    barr();
    // phase 3
    MMQ(1, 1, bf1);
    barr();                                                    // reads done before next STAGE overwrites
    buf ^= 1;
  }

  const int r4 = g << 2;
  const int f = flag ? *flag : 1;
  #pragma unroll
  for (int mi8 = 0; mi8 < 8; ++mi8){
    int row = m0 + wm * 128 + mi8 * 16 + r4;
    #pragma unroll
    for (int ni4 = 0; ni4 < 4; ++ni4){
      int col = n0 + wn * 64 + ni4 * 16 + l16;
      #pragma unroll
      for (int j = 0; j < 4; ++j){
        float v = acc[mi8][ni4][j] * oscale;
        if (outp){
          if (f) ((u16*)outp)[(size_t)(row + j) * ldc + col] = f2bf(v);
          else   ((float*)outp)[(size_t)(row + j) * ldc + col] = v;
        } else {
          C[(size_t)(row + j) * ldc + col] = f2bf(v);
        }
      }
    }
  }
}

// ---------------- RoPE from xc cols 2048..2175 (stride 2304); q-part pre-scaled by 1/sqrt(D)*log2e
__global__ void k_rope(const u16* __restrict__ ropes, const void* __restrict__ cosp,
                       const void* __restrict__ sinp, const int* flag,
                       u16* __restrict__ krope, u16* __restrict__ qrope){
  int id = blockIdx.x * 256 + threadIdx.x;
  if (id >= NROWS * 128) return;
  int row = id >> 7, c = id & 127;
  int t = row & (T_ - 1);
  int d = c & 63, i = d & 31;
  float cs, sn;
  if (*flag){ cs = bf2f(((const u16*)cosp)[t * 32 + i]); sn = bf2f(((const u16*)sinp)[t * 32 + i]); }
  else      { cs = ((const float*)cosp)[t * 32 + i];     sn = ((const float*)sinp)[t * 32 + i]; }
  int base = c & 64;
  float t1 = bf2f(ropes[(size_t)row * 2304 + base + i]);
  float t2 = bf2f(ropes[(size_t)row * 2304 + base + 32 + i]);
  float v = (d < 32) ? (t1 * cs - t2 * sn) : (t2 * cs + t1 * sn);
  if (c >= 64) v *= 0.12753139626374414f;   // 1/sqrt(128) * log2(e), folded into q
  ((c < 64) ? krope : qrope)[(size_t)row * 64 + d] = f2bf(v);
}

// ---------------- causal flash attention, swapped-QK^T register softmax,
// XCD-partitioned tickets: xcd = blockIdx.x & 7 owns bh in [4*xcd, 4*xcd+4)
// -> per-XCD KV working set ~3.3MB fits its private 4MB L2. 128 items/partition.
__global__ __launch_bounds__(256, 2) void k_attn(const u16* __restrict__ qP,
                                                 const u16* __restrict__ kvP,
                                                 const u16* __restrict__ vT,
                                                 const u16* __restrict__ krope,
                                                 const u16* __restrict__ qrope,
                                                 u16* __restrict__ aout,
                                                 int* __restrict__ ticket){
  __shared__ alignas(16) u16 smem[32768];   // 64 KB -> 2 blocks/CU
  const int tid = threadIdx.x, wid = tid >> 6, lane = tid & 63;
  const int l16 = lane & 15, g = lane >> 4;
  const int lk = g << 3, r4 = g << 2;
  const int sw8 = (l16 & 7) << 3;
  const int xcd = blockIdx.x & 7;

  while (true){
    if (tid == 0) *(int*)&smem[0] = atomicAdd(&ticket[xcd << 4], 1);
    __syncthreads();
    const int it = *(const int*)&smem[0];
    __syncthreads();
    if (it >= 128) break;
    const int qt = 31 - (it >> 2);          // heavy-first within partition
    const int bh = (xcd << 2) + (it & 3), b = bh >> 4, h = bh & 15;
    const int q0 = qt << 6;
    const size_t bT = (size_t)b * T_;
    const u16* kvPb = kvP + bT * 3072 + (h << 6);
    const u16* krb  = krope + bT * 64;
    const u16* vTb  = vT + (size_t)bh * 128 * T_;
    const int qlo = q0 + (wid << 4);
    const int nkv = qt + 1;

    auto STAGE = [&](int buf, int k0){
      const int base = buf << 14;
      #pragma unroll
      for (int r = 0; r < 8; ++r){
        int c = (r << 8) + tid;
        const u16* src;
        if (r < 4){
          int row = c >> 4, cc = c & 15;
          int ccx = (cc & 8) | ((cc & 7) ^ (row & 7));
          int col0 = ccx << 3;
          src = (col0 < 64) ? (kvPb + (size_t)(k0 + row) * 3072 + col0)
                            : (krb  + (size_t)(k0 + row) * 64 + (col0 - 64));
        } else {
          int cv = c - 1024;
          int row = cv >> 3, cc = cv & 7;
          int ccx = cc ^ (row & 7);
          src = vTb + (size_t)row * T_ + k0 + (ccx << 3);
        }
        gld_lds16(src, &smem[base + (((r << 8) + (wid << 6)) << 3)]);
      }
    };

    bf16x8 qf[4];
    {
      size_t grow = bT + qlo + l16;
      #pragma unroll
      for (int ks = 0; ks < 4; ++ks){
        int d = (ks << 5) + lk;
        const u16* src = (ks < 2) ? (qP + grow * 1024 + (h << 6) + d)
                                  : (qrope + grow * 64 + (d - 64));
        qf[ks] = *reinterpret_cast<const bf16x8*>(src);
      }
    }
    f32x4 o[8] = {};
    float m = -3e38f, l = 0.f;

    STAGE(0, 0);
    __syncthreads();
    int cur = 0;

    for (int kv = 0; kv < nkv; ++kv){
      const int k0 = kv << 6;
      if (kv + 1 < nkv) STAGE(cur ^ 1, (kv + 1) << 6);
      const int kb = cur << 14;
      f32x4 s[4] = {};
      #pragma unroll
      for (int ks = 0; ks < 4; ++ks){
        int colsw = ((ks << 5) + lk) ^ sw8;
        #pragma unroll
        for (int n = 0; n < 4; ++n){
          bf16x8 kf = *reinterpret_cast<const bf16x8*>(&smem[kb + ((n << 4) + l16) * 128 + colsw]);
          s[n] = mfma16(kf, qf[ks], s[n]);
        }
      }
      if (k0 == q0){
        const int tq = qlo + l16;
        #pragma unroll
        for (int n = 0; n < 4; ++n)
          #pragma unroll
          for (int j = 0; j < 4; ++j)
            s[n][j] = (k0 + (n << 4) + r4 + j <= tq) ? s[n][j] : -3e38f;
      }
      float mx;
      {
        float a0 = fmaxf(fmaxf(s[0][0], s[0][1]), fmaxf(s[0][2], s[0][3]));
        float a1 = fmaxf(fmaxf(s[1][0], s[1][1]), fmaxf(s[1][2], s[1][3]));
        float a2 = fmaxf(fmaxf(s[2][0], s[2][1]), fmaxf(s[2][2], s[2][3]));
        float a3 = fmaxf(fmaxf(s[3][0], s[3][1]), fmaxf(s[3][2], s[3][3]));
        mx = fmaxf(fmaxf(a0, a1), fmaxf(a2, a3));
        mx = fmaxf(mx, __shfl_xor(mx, 16));
        mx = fmaxf(mx, __shfl_xor(mx, 32));
      }
      if (__ballot(mx > m + 8.f)){
        float mnew = fmaxf(m, mx);
        float alpha = exp2f(m - mnew);
        m = mnew; l *= alpha;
        #pragma unroll
        for (int j = 0; j < 4; ++j){
          float av = __shfl(alpha, r4 + j);
          #pragma unroll
          for (int db = 0; db < 8; ++db) o[db][j] *= av;
        }
      }
      unsigned w[4][2];
      float rs = 0.f;
      #pragma unroll
      for (int n = 0; n < 4; ++n)
        #pragma unroll
        for (int jh = 0; jh < 2; ++jh){
          float p0 = exp2f(s[n][2*jh]     - m);
          float p1 = exp2f(s[n][2*jh + 1] - m);
          rs += p0 + p1;
          w[n][jh] = cvt_pk_bf16(p0, p1);
        }
      rs += __shfl_xor(rs, 16);
      rs += __shfl_xor(rs, 32);
      l += rs;
      const int srcA = l16 + ((g & 1) << 5);
      const int srcB = srcA + 16;
      const bool hi = (g >= 2);
      bf16x8 pa[2];
      #pragma unroll
      for (int ks2 = 0; ks2 < 2; ++ks2){
        unsigned a0 = __shfl((int)w[2*ks2][0],     srcA);
        unsigned b0 = __shfl((int)w[2*ks2 + 1][0], srcA);
        unsigned a1 = __shfl((int)w[2*ks2][1],     srcA);
        unsigned b1 = __shfl((int)w[2*ks2 + 1][1], srcA);
        unsigned a2 = __shfl((int)w[2*ks2][0],     srcB);
        unsigned b2 = __shfl((int)w[2*ks2 + 1][0], srcB);
        unsigned a3 = __shfl((int)w[2*ks2][1],     srcB);
        unsigned b3 = __shfl((int)w[2*ks2 + 1][1], srcB);
        union { unsigned u[4]; bf16x8 v; } pk;
        pk.u[0] = hi ? b0 : a0;
        pk.u[1] = hi ? b1 : a1;
        pk.u[2] = hi ? b2 : a2;
        pk.u[3] = hi ? b3 : a3;
        pa[ks2] = pk.v;
      }
      #pragma unroll
      for (int ks2 = 0; ks2 < 2; ++ks2){
        int colsw = ((ks2 << 5) + lk) ^ sw8;
        #pragma unroll
        for (int db = 0; db < 8; ++db){
          bf16x8 vb = *reinterpret_cast<const bf16x8*>(&smem[kb + 8192 + ((db << 4) + l16) * 64 + colsw]);
          o[db] = mfma16(pa[ks2], vb, o[db]);
        }
      }
      __syncthreads();
      cur ^= 1;
    }
    #pragma unroll
    for (int j = 0; j < 4; ++j){
      float lv = __shfl(l, r4 + j);
      float rinv = 1.f / lv;
      const int tq = qlo + r4 + j;
      u16* dst = aout + (bT + tq) * 2048 + (h << 7) + l16;
      #pragma unroll
      for (int db = 0; db < 8; ++db)
        dst[db << 4] = f2bf(o[db][j] * rinv);
    }
  }
}

extern "C" void kernel_launch(void* const* d_in, const int* in_sizes, int n_in,
                              void* d_out, int out_size, void* d_ws, size_t ws_size,
                              hipStream_t stream){
  const void* x       = d_in[0];
  const void* cosp    = d_in[1];
  const void* sinp    = d_in[2];
  const void* w_kv    = d_in[3];
  const void* w_kdec  = d_in[4];
  const void* w_vdec  = d_in[5];
  const void* w_qc    = d_in[6];
  const void* w_qdec  = d_in[7];
  const void* w_krope = d_in[8];
  const void* w_qrope = d_in[9];
  const void* w_o     = d_in[10];

  char* ws = (char*)d_ws;
  size_t off = 0;
  auto alloc = [&](size_t bytes){ void* p = ws + off; off += (bytes + 255) & ~(size_t)255; return p; };
  int* flag     = (int*)alloc(256);
  int* ticket   = (int*)alloc(1024);                         // 8 tickets, stride 16 ints
  u16* x_bf     = (u16*)alloc((size_t)NROWS * DIM_ * 2);
  u16* w_c1T    = (u16*)alloc((size_t)2304 * DIM_ * 2);      // [kvT(512); qcT(1536); kropeT(64); qropeT(64); pad(128)] x 2048
  u16* w_kvdT   = (u16*)alloc((size_t)3072 * DC_ * 2);       // [kdecPackedT(1024); vdecT(2048)] x 512
  u16* w_qdPT   = (u16*)alloc((size_t)1024 * DCQ_ * 2);      // packed qdecT (1024 x 1536)
  u16* w_oT     = (u16*)alloc((size_t)DIM_ * DIM_ * 2);
  u16* xc       = (u16*)alloc((size_t)NROWS * 2304 * 2);     // [c_kv(512) | c_q(1536) | ropes(128) | pad(128)]
  u16* qP       = (u16*)alloc((size_t)NROWS * 1024 * 2);     // packed q decode (pre-scaled)
  u16* kvP      = (u16*)alloc((size_t)NROWS * 3072 * 2);     // [kPacked(1024) | v(2048)]
  u16* krope    = (u16*)alloc((size_t)NROWS * 64 * 2);
  u16* qrope    = (u16*)alloc((size_t)NROWS * 64 * 2);       // pre-scaled
  u16* vT       = (u16*)alloc((size_t)32 * 128 * T_ * 2);    // [bh][d][t]
  u16* aout     = (u16*)alloc((size_t)NROWS * DIM_ * 2);
  (void)in_sizes; (void)n_in; (void)out_size; (void)ws_size;

  const float SC2 = 0.12753139626374414f;   // 1/sqrt(128) * log2(e)

  hipLaunchKernelGGL(k_detect, dim3(1), dim3(128), 0, stream, (const u16*)cosp, flag, ticket);

  int n4 = NROWS * DIM_ / 4;
  hipLaunchKernelGGL(k_conv, dim3((n4 + 255) / 256), dim3(256), 0, stream, x, x_bf, n4, flag);

  // merged weight transposes (one launch, 2880 blocks)
  TPack tp;
  tp.d[0] = { w_kv,    w_c1T,                        512,  2048, 64,  8,  0    };
  tp.d[1] = { w_qc,    w_c1T + (size_t)512 * 2048,   1536, 2048, 64,  24, 256  };
  tp.d[2] = { w_krope, w_c1T + (size_t)2048 * 2048,  64,   2048, 64,  1,  1024 };
  tp.d[3] = { w_qrope, w_c1T + (size_t)2112 * 2048,  64,   2048, 64,  1,  1056 };
  tp.d[4] = { w_kdec,  w_kvdT,                       2048, 512,  128, 16, 1088 };
  tp.d[5] = { w_vdec,  w_kvdT + (size_t)1024 * 512,  2048, 512,  64,  32, 1216 };
  tp.d[6] = { w_qdec,  w_qdPT,                       2048, 1536, 128, 16, 1472 };
  tp.d[7] = { w_o,     w_oT,                         2048, 2048, 64,  32, 1856 };
  hipLaunchKernelGGL(k_transpose8, dim3(2880), dim3(256), 0, stream, tp, flag);

  // G13: xc = x @ [w_kv | w_qc | w_krope | w_qrope | pad]  (4096 x 2304, K=2048)
  hipLaunchKernelGGL(k_gemm256, dim3(16, 9), dim3(512), 0, stream,
                     x_bf, DIM_, w_c1T, DIM_, xc, 2304, 1.0f,
                     x_bf, DIM_, w_c1T, DIM_, xc, 2304, 1.0f,
                     9, (void*)nullptr, (const int*)nullptr);
  // G2 + G4 grouped (256 blocks):
  hipLaunchKernelGGL(k_gemm256, dim3(16, 16), dim3(512), 0, stream,
                     xc, 2304, w_kvdT, DC_, kvP, 3072, 1.0f,
                     xc + 512, 2304, w_qdPT, DCQ_, qP, 1024, SC2,
                     12, (void*)nullptr, (const int*)nullptr);
  // RoPE (q-part pre-scaled)
  hipLaunchKernelGGL(k_rope, dim3(NROWS * 128 / 256), dim3(256), 0, stream,
                     xc + 2048, cosp, sinp, flag, krope, qrope);
  // vT[bh][d][t]
  hipLaunchKernelGGL(k_vt, dim3(T_/64, 2, 32), dim3(256), 0, stream, kvP, vT);
  // attention (persistent, 512 worker blocks = 2/CU, XCD-partitioned tickets)
  hipLaunchKernelGGL(k_attn, dim3(512), dim3(256), 0, stream,
                     qP, kvP, vT, krope, qrope, aout, ticket);
  // G5: out = aout @ w_o  (4096 x 2048, K=2048; writes d_out, dtype per flag)
  hipLaunchKernelGGL(k_gemm256, dim3(16, 8), dim3(512), 0, stream,
                     aout, DIM_, w_oT, DIM_, (u16*)nullptr, DIM_, 1.0f,
                     aout, DIM_, w_oT, DIM_, (u16*)nullptr, DIM_, 1.0f,
                     8, d_out, (const int*)flag);
}